// Round 14
// baseline (476.479 us; speedup 1.0000x reference)
//
#include <hip/hip_runtime.h>
#include <hip/hip_bf16.h>
#include <hip/hip_cooperative_groups.h>
#include <math.h>

namespace cg = cooperative_groups;

#define HW_   65536
#define B_    2
#define Q_    100
#define C_    134
#define T_    20
#define NHUN  100
#define MT_   7            // M-tiles of 16 queries (112 >= 100)
#define KSB   128          // K-split blocks (fallback path)
#define KSB2  64           // K-split blocks (mega path)
#define PREC  1088         // part record stride (1024 frag + 16 F + 16 P + pad)
#define CPAD  21           // padded cost row stride (floats) in hungarian LDS

typedef __attribute__((ext_vector_type(8))) short bf16x8;
typedef __attribute__((ext_vector_type(4))) float f32x4;

// ws layout (float units) — sized for the larger (fallback) configuration
#define LABPS_OFF  0                    // [2][20][8]
#define CC_OFF     512                  // [200][20] (fallback path only)
#define COST_OFF   4608                 // [200][20]
#define BASE_END   8704
#define LABT_HI_F  BASE_END                         // 2*20*65536 ushort = 1,310,720 floats
#define PART_OFF   (LABT_HI_F + 1310720)            // up to 1792 records * 1088 floats
#define CSUM_OFF   (PART_OFF + B_ * KSB * MT_ * PREC)   // 14*1056
#define WS_END_F   (CSUM_OFF + B_ * MT_ * 1056)

__device__ inline unsigned short f2bf(float f) {
    unsigned int u = __builtin_bit_cast(unsigned int, f);
    u += 0x7FFFu + ((u >> 16) & 1u);               // RNE
    return (unsigned short)(u >> 16);
}
__device__ inline float softplusf(float x) {
    float ax = fabsf(x);
    return fmaxf(x, 0.0f) + log1pf(expf(-ax));
}

// ==================== MEGA KERNEL (cooperative, 896 blocks x 256 thr) ====================
__global__ __launch_bounds__(256, 4) void mega_kernel(
        const float* __restrict__ mq, const float* __restrict__ cl,
        const float* __restrict__ ml, const int* __restrict__ labels,
        unsigned short* __restrict__ labT, float* __restrict__ lab_ps,
        float* __restrict__ part, float* __restrict__ Csum,
        float* __restrict__ cost, int* __restrict__ out) {
    cg::grid_group grid = cg::this_grid();
    int bid = blockIdx.x;
    int tid = threadIdx.x;
    int wave = tid >> 6, lane = tid & 63;

    __shared__ __align__(16) char smem[17408];

    // ---------- phase 0: lab_prep (blocks 0..319) ----------
    if (bid < 320) {
        int b = bid / 160, rem = bid % 160;
        int t = rem / 8, ksl = rem % 8;
        const float* src = ml + (size_t)(b * T_ + t) * 262144;
        size_t dst = ((size_t)(b * T_ + t)) << 16;
        float acc = 0.f;
        for (int it = 0; it < 8; ++it) {
            int k = ksl * 8192 + it * 1024 + tid * 4;
            int r = k >> 8, c = k & 255;
            const float* s = src + r * 1024 + 2 * c;
            float4 u = *(const float4*)s;
            float4 w = *(const float4*)(s + 4);
            float v[4] = {u.x, u.z, w.x, w.z};
            unsigned short h[4];
#pragma unroll
            for (int e = 0; e < 4; ++e) { h[e] = f2bf(v[e]); acc += v[e]; }
            *(ushort4*)(labT + dst + k) = make_ushort4(h[0], h[1], h[2], h[3]);
        }
        for (int off = 32; off > 0; off >>= 1) acc += __shfl_down(acc, off);
        float* sb = (float*)smem;
        if (lane == 0) sb[wave] = acc;
        __syncthreads();
        if (tid == 0) lab_ps[(b * T_ + t) * 8 + ksl] = sb[0] + sb[1] + sb[2] + sb[3];
    }
    grid.sync();

    // ---------- phase 1: focal MFMA (all 896 blocks; KSB2=64, 1024 k/block) ----------
    {
        int mt  = bid % MT_;
        int rem = bid / MT_;
        int ks  = rem % KSB2;
        int b   = rem / KSB2;
        int lg = lane >> 4, lr = lane & 15;

        int q = mt * 16 + lr;
        bool qok = (q < Q_);
        const float* xrow = mq + ((size_t)(b * Q_ + (qok ? q : 0)) << 16);
        int koff = ks * 1024 + wave * 256 + lg * 8;

        const unsigned short* b1 = labT + (((size_t)(b * T_ + lr)) << 16);
        const unsigned short* b2 = labT + (((size_t)(b * T_ + 16 + (lr & 3))) << 16);
        bool n2row = (lr < 4);

        f32x4 accD0 = {0,0,0,0}, accD1 = {0,0,0,0};
        f32x4 accP0 = {0,0,0,0}, accP1 = {0,0,0,0};
        float F = 0.f, P = 0.f;

        bf16x8 zer;
#pragma unroll
        for (int e = 0; e < 8; ++e) zer[e] = 0;

        for (int kk = 0; kk < 8; ++kk) {
            int kb = koff + kk * 32;
            float4 u0 = *(const float4*)(xrow + kb);
            float4 u1 = *(const float4*)(xrow + kb + 4);
            float xv[8] = {u0.x, u0.y, u0.z, u0.w, u1.x, u1.y, u1.z, u1.w};

            bf16x8 f1 = *(const bf16x8*)(b1 + kb);
            bf16x8 f2 = n2row ? *(const bf16x8*)(b2 + kb) : zer;

            bf16x8 dh, ph;
#pragma unroll
            for (int e = 0; e < 8; ++e) {
                float x  = xv[e];
                float ax = fabsf(x);
                float a  = __expf(-ax);
                float rr = 1.0f / (1.0f + a);
                float p  = (x >= 0.f) ? rr : a * rr;
                float om = (x >= 0.f) ? a * rr : rr;
                float l1 = __logf(1.0f + a);
                float spn = fmaxf(-x, 0.f) + l1;
                float spp = spn + x;
                float fp = 0.25f * om * om * spn;
                float fn = 0.75f * p * p * spp;
                F += fn; P += p;
                dh[e] = (short)f2bf(fp - fn);
                ph[e] = (short)f2bf(p);
            }
            accD0 = __builtin_amdgcn_mfma_f32_16x16x32_bf16(dh, f1, accD0, 0, 0, 0);
            accD1 = __builtin_amdgcn_mfma_f32_16x16x32_bf16(dh, f2, accD1, 0, 0, 0);
            accP0 = __builtin_amdgcn_mfma_f32_16x16x32_bf16(ph, f1, accP0, 0, 0, 0);
            accP1 = __builtin_amdgcn_mfma_f32_16x16x32_bf16(ph, f2, accP1, 0, 0, 0);
        }

        F += __shfl_down(F, 32); F += __shfl_down(F, 16);
        P += __shfl_down(P, 32); P += __shfl_down(P, 16);

        float (*red)[4][64][4] = (float (*)[4][64][4])smem;      // 16 KB
        float (*fpb)[2][16]    = (float (*)[2][16])(smem + 16384);
#pragma unroll
        for (int r = 0; r < 4; ++r) {
            red[wave][0][lane][r] = accD0[r];
            red[wave][1][lane][r] = accD1[r];
            red[wave][2][lane][r] = accP0[r];
            red[wave][3][lane][r] = accP1[r];
        }
        if (lane < 16) { fpb[wave][0][lane] = F; fpb[wave][1][lane] = P; }
        __syncthreads();
        {
            int e4 = tid;                      // 256 float4 groups = 1024 floats
            int f  = e4 >> 6;
            int l2 = e4 & 63;
            float4 s;
            s.x = red[0][f][l2][0] + red[1][f][l2][0] + red[2][f][l2][0] + red[3][f][l2][0];
            s.y = red[0][f][l2][1] + red[1][f][l2][1] + red[2][f][l2][1] + red[3][f][l2][1];
            s.z = red[0][f][l2][2] + red[1][f][l2][2] + red[2][f][l2][2] + red[3][f][l2][2];
            s.w = red[0][f][l2][3] + red[1][f][l2][3] + red[2][f][l2][3] + red[3][f][l2][3];
            *(float4*)(part + (size_t)bid * PREC + e4 * 4) = s;
        }
        if (tid < 16)
            part[(size_t)bid * PREC + 1024 + tid] =
                fpb[0][0][tid] + fpb[1][0][tid] + fpb[2][0][tid] + fpb[3][0][tid];
        else if (tid < 32) {
            int l = tid - 16;
            part[(size_t)bid * PREC + 1040 + l] =
                fpb[0][1][l] + fpb[1][1][l] + fpb[2][1][l] + fpb[3][1][l];
        }
    }
    grid.sync();

    // ---------- phase 2: K-split reduction (blocks 0..461) ----------
    if (bid < 462) {
        int bm   = bid / 33;            // 0..13
        int esl  = bid % 33;
        int mt   = bm % MT_;
        int b    = bm / MT_;
        int epos = tid & 31;
        int grp  = tid >> 5;            // 0..7
        int e    = esl * 32 + epos;

        const float* base = part + (size_t)((b * KSB2) * MT_ + mt) * PREC + e;
        float s = 0.f;
        for (int k = 0; k < 8; ++k)
            s += base[(size_t)(grp * 8 + k) * MT_ * PREC];
        float (*r8)[33] = (float (*)[33])smem;
        r8[grp][epos] = s;
        __syncthreads();
        if (tid < 32) {
            float tot = 0.f;
            for (int g = 0; g < 8; ++g) tot += r8[g][tid];
            Csum[(size_t)bm * 1056 + e] = tot;
        }
    }
    grid.sync();

    // ---------- phase 3: compose (blocks 0..13) ----------
    if (bid < 14) {
        int bm = bid;
        int mt = bm % MT_;
        int b  = bm / MT_;
        int q0 = mt * 16;

        float (*sl)[136] = (float (*)[136])smem;            // 8704 B
        float* mx = (float*)(smem + 8704);
        float* se = (float*)(smem + 8768);
        int*   lbl = (int*)(smem + 8832);
        for (int e = tid; e < 16 * C_; e += 256) {
            int qm = e / C_, c = e % C_;
            int q = q0 + qm;
            sl[qm][c] = (q < Q_) ? cl[(size_t)(b * Q_ + q) * C_ + c] : 0.f;
        }
        if (tid < T_) lbl[tid] = labels[b * T_ + tid];
        __syncthreads();
        if (tid < 16) {
            float m = -INFINITY;
            for (int c = 0; c < C_; ++c) m = fmaxf(m, sl[tid][c]);
            float s = 0.f;
            for (int c = 0; c < C_; ++c) s += expf(sl[tid][c] - m);
            mx[tid] = m; se[tid] = s;
        }
        __syncthreads();
        for (int e = tid; e < 320; e += 256) {
            int qm = e / T_, t = e % T_;
            int q = q0 + qm;
            if (qm < 16 && q < Q_) {
                const float* C = Csum + (size_t)bm * 1056;
                int nt   = t >> 4;
                int ln   = ((qm >> 2) << 4) | (t & 15);
                int reg  = qm & 3;
                float Sd = C[(0 + nt) * 256 + ln * 4 + reg];
                float Sp = C[(2 + nt) * 256 + ln * 4 + reg];
                float Fv = C[1024 + qm];
                float Pv = C[1040 + qm];
                float L = 0.f;
                for (int s8 = 0; s8 < 8; ++s8) L += lab_ps[(b * T_ + t) * 8 + s8];
                float ccv = -expf(sl[qm][lbl[t]] - mx[qm]) / se[qm];
                float cm = (Sd + Fv) * (1.0f / (float)HW_);
                float cd = 1.0f - (2.0f * Sp + 1.0f) / (Pv + L + 1.0f);
                cost[(size_t)(b * Q_ + q) * T_ + t] = cm + cd + ccv;
            }
        }
    }
    grid.sync();

    // ---------- phase 4: hungarian (blocks 0..1, wave 0 solves) ----------
    if (bid < 2) {
        int b = bid;
        float* csh = (float*)smem;                 // [Q_*CPAD]
        int*   psh = (int*)(smem + Q_ * CPAD * 4); // [NHUN+1]

        for (int j = tid; j < Q_; j += 256) {
#pragma unroll
            for (int t = 0; t < T_; ++t)
                csh[j * CPAD + t] = cost[b * Q_ * T_ + j * T_ + t];
        }
        __syncthreads();

        if (tid < 64) {
            const int ja = lane;
            const int jb = lane + 64;
            const bool ja_ok = (ja >= 1);
            const bool jb_ok = (jb <= NHUN);

            int   p_a = 0, p_b = 0;
            float v_a = 0.f, v_b = 0.f;
            float u_reg = 0.f;

            for (int i = 1; i <= T_; ++i) {
                float ca = ja_ok ? csh[(ja - 1) * CPAD + (i - 1)] : INFINITY;
                float cb = jb_ok ? csh[(jb - 1) * CPAD + (i - 1)] : INFINITY;
                float vmin = fminf(ca, cb);
                for (int off = 32; off > 0; off >>= 1)
                    vmin = fminf(vmin, __shfl_xor(vmin, off));
                unsigned long long ba = __ballot(ca == vmin);
                int j1 = ba ? (__ffsll(ba) - 1) : (__ffsll(__ballot(cb == vmin)) - 1 + 64);
                if (lane == i) u_reg = vmin;
                int pj = __shfl((j1 < 64) ? p_a : p_b, j1 & 63);
                if (pj == 0) {
                    if (j1 < 64) { if (lane == j1) p_a = i; }
                    else         { if (lane == j1 - 64) p_b = i; }
                }
            }

            for (int i = 1; i <= T_; ++i) {
                bool mine = (p_a == i) || (p_b == i);
                if (__ballot(mine)) continue;

                float m_a = INFINITY, m_b = INFINITY;
                int   way_a = 0, way_b = 0;
                bool  us_a = false, us_b = false;
                bool  in_tree = (lane == i);
                int   j0 = 0, jf;

                while (true) {
                    int i0 = (j0 == 0) ? i : __shfl((j0 < 64) ? p_a : p_b, j0 & 63);
                    if (lane == i0) in_tree = true;
                    float ui0 = __shfl(u_reg, i0);
                    if (ja == j0) us_a = true;
                    if (jb == j0) us_b = true;
                    bool fa = ja_ok && !us_a;
                    bool fb = jb_ok && !us_b;
                    if (fa) {
                        float cur = csh[(ja - 1) * CPAD + (i0 - 1)] - ui0 - v_a;
                        if (cur < m_a) { m_a = cur; way_a = j0; }
                    }
                    if (fb) {
                        float cur = csh[(jb - 1) * CPAD + (i0 - 1)] - ui0 - v_b;
                        if (cur < m_b) { m_b = cur; way_b = j0; }
                    }
                    float ca = fa ? m_a : INFINITY;
                    float cb = fb ? m_b : INFINITY;
                    float vmin = fminf(ca, cb);
                    for (int off = 32; off > 0; off >>= 1)
                        vmin = fminf(vmin, __shfl_xor(vmin, off));
                    unsigned long long ba = __ballot(ca == vmin);
                    int j1 = ba ? (__ffsll(ba) - 1) : (__ffsll(__ballot(cb == vmin)) - 1 + 64);
                    float delta = vmin;
                    if (us_a) v_a -= delta; else m_a -= delta;
                    if (us_b) v_b -= delta; else m_b -= delta;
                    if (in_tree) u_reg += delta;
                    j0 = j1;
                    int pj0 = __shfl((j0 < 64) ? p_a : p_b, j0 & 63);
                    if (pj0 == 0) { jf = j0; break; }
                }
                int jj = jf;
                while (jj) {
                    int wv = __shfl((jj < 64) ? way_a : way_b, jj & 63);
                    int pn = (wv == 0) ? i : __shfl((wv < 64) ? p_a : p_b, wv & 63);
                    if (jj < 64) { if (lane == jj) p_a = pn; }
                    else         { if (lane == jj - 64) p_b = pn; }
                    jj = wv;
                }
            }

            if (ja_ok) psh[ja] = p_a;
            if (jb_ok) psh[jb] = p_b;
            if (lane == 0) psh[0] = 0;
        }
        __syncthreads();
        if (tid == 0) {
            int* ob = out + b * 2 * T_;
            int k = 0;
            for (int j = 1; j <= NHUN; ++j) {
                if (psh[j] != 0) { ob[k] = j - 1; ob[T_ + k] = psh[j] - 1; ++k; }
            }
        }
    }
}

// ==================== FALLBACK KERNELS (R13-proven 5-kernel path) ====================
__global__ void lab_prep_kernel(const float* __restrict__ ml, unsigned short* __restrict__ labT,
                                float* __restrict__ lab_ps, int writeT) {
    int b = blockIdx.x, t = blockIdx.y, ksl = blockIdx.z;
    int tid = threadIdx.x;
    const float* src = ml + (size_t)(b * T_ + t) * 262144;
    size_t dst = ((size_t)(b * T_ + t)) << 16;
    float acc = 0.f;
    for (int it = 0; it < 8; ++it) {
        int k = ksl * 8192 + it * 1024 + tid * 4;
        int r = k >> 8, c = k & 255;
        const float* s = src + r * 1024 + 2 * c;
        float4 u = *(const float4*)s;
        float4 w = *(const float4*)(s + 4);
        float v[4] = {u.x, u.z, w.x, w.z};
        unsigned short h[4];
#pragma unroll
        for (int e = 0; e < 4; ++e) { h[e] = f2bf(v[e]); acc += v[e]; }
        if (writeT) *(ushort4*)(labT + dst + k) = make_ushort4(h[0], h[1], h[2], h[3]);
    }
    for (int off = 32; off > 0; off >>= 1) acc += __shfl_down(acc, off);
    __shared__ float sb[4];
    int wid = tid >> 6, lane = tid & 63;
    if (lane == 0) sb[wid] = acc;
    __syncthreads();
    if (tid == 0) lab_ps[(b * T_ + t) * 8 + ksl] = sb[0] + sb[1] + sb[2] + sb[3];
}

__global__ void class_cost_kernel(const float* __restrict__ cl, const int* __restrict__ labels,
                                  float* __restrict__ cc) {
    int bq  = blockIdx.x;
    int b   = bq / Q_;
    int tid = threadIdx.x;
    __shared__ float sl[C_];
    const float* src = cl + (size_t)bq * C_;
    for (int c = tid; c < C_; c += 64) sl[c] = src[c];
    __syncthreads();
    float mx = -INFINITY;
    for (int c = tid; c < C_; c += 64) mx = fmaxf(mx, sl[c]);
    for (int off = 32; off > 0; off >>= 1) mx = fmaxf(mx, __shfl_xor(mx, off));
    float se = 0.f;
    for (int c = tid; c < C_; c += 64) se += expf(sl[c] - mx);
    for (int off = 32; off > 0; off >>= 1) se += __shfl_xor(se, off);
    float inv = 1.0f / se;
    if (tid < T_) {
        int lbl = labels[b * T_ + tid];
        cc[bq * T_ + tid] = -expf(sl[lbl] - mx) * inv;
    }
}

__global__ __launch_bounds__(256, 4) void focal_mfma_kernel(
        const float* __restrict__ mq, const unsigned short* __restrict__ labT,
        float* __restrict__ part) {
    int idx = blockIdx.x;
    int mt  = idx % MT_;
    int rem = idx / MT_;
    int ks  = rem % KSB;
    int b   = rem / KSB;
    int tid  = threadIdx.x;
    int wave = tid >> 6, lane = tid & 63;
    int lg = lane >> 4, lr = lane & 15;

    int q = mt * 16 + lr;
    bool qok = (q < Q_);
    const float* xrow = mq + ((size_t)(b * Q_ + (qok ? q : 0)) << 16);
    int koff = ks * 512 + wave * 128 + lg * 8;

    const unsigned short* b1 = labT + (((size_t)(b * T_ + lr)) << 16);
    const unsigned short* b2 = labT + (((size_t)(b * T_ + 16 + (lr & 3))) << 16);
    bool n2row = (lr < 4);

    bf16x8 zer;
#pragma unroll
    for (int e = 0; e < 8; ++e) zer[e] = 0;

    f32x4 accD0 = {0,0,0,0}, accD1 = {0,0,0,0};
    f32x4 accP0 = {0,0,0,0}, accP1 = {0,0,0,0};
    float F = 0.f, P = 0.f;

#pragma unroll
    for (int kk = 0; kk < 4; ++kk) {
        int kb = koff + kk * 32;
        float4 u0 = *(const float4*)(xrow + kb);
        float4 u1 = *(const float4*)(xrow + kb + 4);
        bf16x8 f1 = *(const bf16x8*)(b1 + kb);
        bf16x8 f2 = n2row ? *(const bf16x8*)(b2 + kb) : zer;
        float xv[8] = {u0.x, u0.y, u0.z, u0.w, u1.x, u1.y, u1.z, u1.w};
        bf16x8 dh, ph;
#pragma unroll
        for (int e = 0; e < 8; ++e) {
            float x  = xv[e];
            float ax = fabsf(x);
            float a  = __expf(-ax);
            float rr = 1.0f / (1.0f + a);
            float p  = (x >= 0.f) ? rr : a * rr;
            float om = (x >= 0.f) ? a * rr : rr;
            float l1 = __logf(1.0f + a);
            float spn = fmaxf(-x, 0.f) + l1;
            float spp = spn + x;
            float fp = 0.25f * om * om * spn;
            float fn = 0.75f * p * p * spp;
            F += fn; P += p;
            dh[e] = (short)f2bf(fp - fn);
            ph[e] = (short)f2bf(p);
        }
        accD0 = __builtin_amdgcn_mfma_f32_16x16x32_bf16(dh, f1, accD0, 0, 0, 0);
        accD1 = __builtin_amdgcn_mfma_f32_16x16x32_bf16(dh, f2, accD1, 0, 0, 0);
        accP0 = __builtin_amdgcn_mfma_f32_16x16x32_bf16(ph, f1, accP0, 0, 0, 0);
        accP1 = __builtin_amdgcn_mfma_f32_16x16x32_bf16(ph, f2, accP1, 0, 0, 0);
    }

    F += __shfl_down(F, 32); F += __shfl_down(F, 16);
    P += __shfl_down(P, 32); P += __shfl_down(P, 16);

    __shared__ float red[4][4][64][4];
    __shared__ float fpb[4][2][16];
#pragma unroll
    for (int r = 0; r < 4; ++r) {
        red[wave][0][lane][r] = accD0[r];
        red[wave][1][lane][r] = accD1[r];
        red[wave][2][lane][r] = accP0[r];
        red[wave][3][lane][r] = accP1[r];
    }
    if (lane < 16) { fpb[wave][0][lane] = F; fpb[wave][1][lane] = P; }
    __syncthreads();
    {
        int e4 = tid;
        int f  = e4 >> 6;
        int l2 = e4 & 63;
        float4 s;
        s.x = red[0][f][l2][0] + red[1][f][l2][0] + red[2][f][l2][0] + red[3][f][l2][0];
        s.y = red[0][f][l2][1] + red[1][f][l2][1] + red[2][f][l2][1] + red[3][f][l2][1];
        s.z = red[0][f][l2][2] + red[1][f][l2][2] + red[2][f][l2][2] + red[3][f][l2][2];
        s.w = red[0][f][l2][3] + red[1][f][l2][3] + red[2][f][l2][3] + red[3][f][l2][3];
        *(float4*)(part + (size_t)idx * PREC + e4 * 4) = s;
    }
    if (tid < 16)
        part[(size_t)idx * PREC + 1024 + tid] =
            fpb[0][0][tid] + fpb[1][0][tid] + fpb[2][0][tid] + fpb[3][0][tid];
    else if (tid < 32) {
        int l = tid - 16;
        part[(size_t)idx * PREC + 1040 + l] =
            fpb[0][1][l] + fpb[1][1][l] + fpb[2][1][l] + fpb[3][1][l];
    }
}

__global__ __launch_bounds__(256) void reduce_part_kernel(const float* __restrict__ part,
                                                          float* __restrict__ Csum) {
    int bm   = blockIdx.x;
    int mt   = bm % MT_;
    int b    = bm / MT_;
    int tid  = threadIdx.x;
    int epos = tid & 31;
    int grp  = tid >> 5;
    int e    = blockIdx.y * 32 + epos;

    const float* base = part + (size_t)((b * KSB) * MT_ + mt) * PREC + e;
    float s = 0.f;
    for (int k = 0; k < 16; ++k)
        s += base[(size_t)(grp * 16 + k) * MT_ * PREC];
    __shared__ float red[8][33];
    red[grp][epos] = s;
    __syncthreads();
    if (tid < 32) {
        float tot = 0.f;
        for (int g = 0; g < 8; ++g) tot += red[g][tid];
        Csum[(size_t)bm * 1056 + e] = tot;
    }
}

__global__ __launch_bounds__(320) void compose_kernel(
        const float* __restrict__ Csum, const float* __restrict__ cl,
        const int* __restrict__ labels, const float* __restrict__ lab_ps,
        float* __restrict__ cost) {
    int bm = blockIdx.x;
    int mt = bm % MT_;
    int b  = bm / MT_;
    int tid = threadIdx.x;
    int q0 = mt * 16;

    __shared__ float sl[16][136];
    __shared__ float mx[16], se[16];
    __shared__ int   lbl[T_];
    for (int e = tid; e < 16 * C_; e += 320) {
        int qm = e / C_, c = e % C_;
        int q = q0 + qm;
        sl[qm][c] = (q < Q_) ? cl[(size_t)(b * Q_ + q) * C_ + c] : 0.f;
    }
    if (tid < T_) lbl[tid] = labels[b * T_ + tid];
    __syncthreads();
    if (tid < 16) {
        float m = -INFINITY;
        for (int c = 0; c < C_; ++c) m = fmaxf(m, sl[tid][c]);
        float s = 0.f;
        for (int c = 0; c < C_; ++c) s += expf(sl[tid][c] - m);
        mx[tid] = m; se[tid] = s;
    }
    __syncthreads();

    int qm = tid / T_, t = tid % T_;
    int q = q0 + qm;
    if (qm < 16 && q < Q_) {
        const float* C = Csum + (size_t)bm * 1056;
        int nt   = t >> 4;
        int lane = ((qm >> 2) << 4) | (t & 15);
        int reg  = qm & 3;
        float Sd = C[(0 + nt) * 256 + lane * 4 + reg];
        float Sp = C[(2 + nt) * 256 + lane * 4 + reg];
        float F  = C[1024 + qm];
        float P  = C[1040 + qm];
        float L = 0.f;
        for (int s8 = 0; s8 < 8; ++s8) L += lab_ps[(b * T_ + t) * 8 + s8];
        float ccv = -expf(sl[qm][lbl[t]] - mx[qm]) / se[qm];
        float cm = (Sd + F) * (1.0f / (float)HW_);
        float cd = 1.0f - (2.0f * Sp + 1.0f) / (P + L + 1.0f);
        cost[(size_t)(b * Q_ + q) * T_ + t] = cm + cd + ccv;
    }
}

__global__ __launch_bounds__(1024) void mask_cost_mono_kernel(
        const float* __restrict__ mq, const float* __restrict__ ml,
        const float* __restrict__ cc, const float* __restrict__ lab_ps,
        float* __restrict__ cost) {
    int bq  = blockIdx.x;
    int b   = bq / Q_;
    int tid = threadIdx.x;
    const float* xb  = mq + (size_t)bq * HW_;
    const float* mlb = ml + (size_t)b * T_ * 262144;
    float s1[T_], s2[T_];
#pragma unroll
    for (int t = 0; t < T_; ++t) { s1[t] = 0.f; s2[t] = 0.f; }
    float F = 0.f, P = 0.f;
    for (int k = tid; k < HW_; k += 1024) {
        int i = k >> 8, j = k & 255;
        float x = xb[k];
        float p = 1.0f / (1.0f + expf(-x));
        float spn = softplusf(-x);
        float spp = softplusf(x);
        float om = 1.0f - p;
        float fp = 0.25f * om * om * spn;
        float fn = 0.75f * p * p * spp;
        F += fn; P += p;
        float diff = fp - fn;
        int off0 = i * 1024 + 2 * j;
#pragma unroll
        for (int t = 0; t < T_; ++t) {
            float lab = mlb[t * 262144 + off0];
            s1[t] = fmaf(diff, lab, s1[t]);
            s2[t] = fmaf(p,    lab, s2[t]);
        }
    }
    __shared__ float sbuf[16][42];
    int wid = tid >> 6, lane = tid & 63;
#pragma unroll
    for (int t = 0; t < T_; ++t) {
        for (int off = 32; off > 0; off >>= 1) {
            s1[t] += __shfl_down(s1[t], off);
            s2[t] += __shfl_down(s2[t], off);
        }
    }
    for (int off = 32; off > 0; off >>= 1) { F += __shfl_down(F, off); P += __shfl_down(P, off); }
    if (lane == 0) {
#pragma unroll
        for (int t = 0; t < T_; ++t) { sbuf[wid][t] = s1[t]; sbuf[wid][T_ + t] = s2[t]; }
        sbuf[wid][40] = F; sbuf[wid][41] = P;
    }
    __syncthreads();
    if (tid < T_) {
        float S1 = 0.f, S2 = 0.f, Fs = 0.f, Ps = 0.f;
        for (int w = 0; w < 16; ++w) {
            S1 += sbuf[w][tid]; S2 += sbuf[w][T_ + tid];
            Fs += sbuf[w][40];  Ps += sbuf[w][41];
        }
        float L = 0.f;
        for (int sl = 0; sl < 8; ++sl) L += lab_ps[(b * T_ + tid) * 8 + sl];
        float cm = (S1 + Fs) * (1.0f / (float)HW_);
        float cd = 1.0f - (2.0f * S2 + 1.0f) / (Ps + L + 1.0f);
        cost[bq * T_ + tid] = cm + cd + cc[bq * T_ + tid];
    }
}

__global__ __launch_bounds__(64) void hungarian_kernel(const float* __restrict__ cost,
                                                       int* __restrict__ out) {
    int b    = blockIdx.x;
    int lane = threadIdx.x;

    __shared__ float csh[Q_ * CPAD];
    __shared__ int   psh[NHUN + 1];

    for (int j = lane; j < Q_; j += 64) {
#pragma unroll
        for (int t = 0; t < T_; ++t)
            csh[j * CPAD + t] = cost[b * Q_ * T_ + j * T_ + t];
    }
    __syncthreads();

    const int ja = lane;
    const int jb = lane + 64;
    const bool ja_ok = (ja >= 1);
    const bool jb_ok = (jb <= NHUN);

    int   p_a = 0, p_b = 0;
    float v_a = 0.f, v_b = 0.f;
    float u_reg = 0.f;

    for (int i = 1; i <= T_; ++i) {
        float ca = ja_ok ? csh[(ja - 1) * CPAD + (i - 1)] : INFINITY;
        float cb = jb_ok ? csh[(jb - 1) * CPAD + (i - 1)] : INFINITY;
        float vmin = fminf(ca, cb);
        for (int off = 32; off > 0; off >>= 1)
            vmin = fminf(vmin, __shfl_xor(vmin, off));
        unsigned long long ba = __ballot(ca == vmin);
        int j1 = ba ? (__ffsll(ba) - 1) : (__ffsll(__ballot(cb == vmin)) - 1 + 64);
        if (lane == i) u_reg = vmin;
        int pj = __shfl((j1 < 64) ? p_a : p_b, j1 & 63);
        if (pj == 0) {
            if (j1 < 64) { if (lane == j1) p_a = i; }
            else         { if (lane == j1 - 64) p_b = i; }
        }
    }

    for (int i = 1; i <= T_; ++i) {
        bool mine = (p_a == i) || (p_b == i);
        if (__ballot(mine)) continue;

        float m_a = INFINITY, m_b = INFINITY;
        int   way_a = 0, way_b = 0;
        bool  us_a = false, us_b = false;
        bool  in_tree = (lane == i);
        int   j0 = 0, jf;

        while (true) {
            int i0 = (j0 == 0) ? i : __shfl((j0 < 64) ? p_a : p_b, j0 & 63);
            if (lane == i0) in_tree = true;
            float ui0 = __shfl(u_reg, i0);
            if (ja == j0) us_a = true;
            if (jb == j0) us_b = true;
            bool fa = ja_ok && !us_a;
            bool fb = jb_ok && !us_b;
            if (fa) {
                float cur = csh[(ja - 1) * CPAD + (i0 - 1)] - ui0 - v_a;
                if (cur < m_a) { m_a = cur; way_a = j0; }
            }
            if (fb) {
                float cur = csh[(jb - 1) * CPAD + (i0 - 1)] - ui0 - v_b;
                if (cur < m_b) { m_b = cur; way_b = j0; }
            }
            float ca = fa ? m_a : INFINITY;
            float cb = fb ? m_b : INFINITY;
            float vmin = fminf(ca, cb);
            for (int off = 32; off > 0; off >>= 1)
                vmin = fminf(vmin, __shfl_xor(vmin, off));
            unsigned long long ba = __ballot(ca == vmin);
            int j1 = ba ? (__ffsll(ba) - 1) : (__ffsll(__ballot(cb == vmin)) - 1 + 64);
            float delta = vmin;
            if (us_a) v_a -= delta; else m_a -= delta;
            if (us_b) v_b -= delta; else m_b -= delta;
            if (in_tree) u_reg += delta;
            j0 = j1;
            int pj0 = __shfl((j0 < 64) ? p_a : p_b, j0 & 63);
            if (pj0 == 0) { jf = j0; break; }
        }
        int jj = jf;
        while (jj) {
            int wv = __shfl((jj < 64) ? way_a : way_b, jj & 63);
            int pn = (wv == 0) ? i : __shfl((wv < 64) ? p_a : p_b, wv & 63);
            if (jj < 64) { if (lane == jj) p_a = pn; }
            else         { if (lane == jj - 64) p_b = pn; }
            jj = wv;
        }
    }

    if (ja_ok) psh[ja] = p_a;
    if (jb_ok) psh[jb] = p_b;
    if (lane == 0) psh[0] = 0;
    __syncthreads();
    if (lane == 0) {
        int* ob = out + b * 2 * T_;
        int k = 0;
        for (int j = 1; j <= NHUN; ++j) {
            if (psh[j] != 0) { ob[k] = j - 1; ob[T_ + k] = psh[j] - 1; ++k; }
        }
    }
}

extern "C" void kernel_launch(void* const* d_in, const int* in_sizes, int n_in,
                              void* d_out, int out_size, void* d_ws, size_t ws_size,
                              hipStream_t stream) {
    const float* mq     = (const float*)d_in[0];   // [2,100,256,256]
    const float* cl     = (const float*)d_in[1];   // [2,100,134]
    const float* ml     = (const float*)d_in[2];   // [2,20,512,512]
    const int*   labels = (const int*)d_in[3];     // [2,20]
    int* out = (int*)d_out;                        // [2,2,20] int32
    float* ws = (float*)d_ws;

    float* lab_ps = ws + LABPS_OFF;
    float* cc     = ws + CC_OFF;
    float* cost   = ws + COST_OFF;

    size_t need = (size_t)WS_END_F * 4;

    if (ws_size >= need) {
        unsigned short* labT = (unsigned short*)(ws + LABT_HI_F);
        float* part = ws + PART_OFF;
        float* Csum = ws + CSUM_OFF;

        void* kargs[] = {(void*)&mq, (void*)&cl, (void*)&ml, (void*)&labels,
                         (void*)&labT, (void*)&lab_ps, (void*)&part, (void*)&Csum,
                         (void*)&cost, (void*)&out};
        hipError_t err = hipLaunchCooperativeKernel((const void*)mega_kernel,
                                                    dim3(B_ * KSB2 * MT_), dim3(256),
                                                    kargs, 0, stream);
        if (err != hipSuccess) {
            (void)hipGetLastError();   // clear
            hipLaunchKernelGGL(lab_prep_kernel,   dim3(B_, T_, 8), dim3(256), 0, stream,
                               ml, labT, lab_ps, 1);
            hipLaunchKernelGGL(focal_mfma_kernel, dim3(B_ * KSB * MT_), dim3(256), 0, stream,
                               mq, labT, part);
            hipLaunchKernelGGL(reduce_part_kernel, dim3(B_ * MT_, 33), dim3(256), 0, stream,
                               part, Csum);
            hipLaunchKernelGGL(compose_kernel,    dim3(B_ * MT_),  dim3(320), 0, stream,
                               Csum, cl, labels, lab_ps, cost);
            hipLaunchKernelGGL(hungarian_kernel,  dim3(B_), dim3(64), 0, stream, cost, out);
        }
    } else {
        hipLaunchKernelGGL(lab_prep_kernel,   dim3(B_, T_, 8), dim3(256), 0, stream,
                           ml, (unsigned short*)ws, lab_ps, 0);
        hipLaunchKernelGGL(class_cost_kernel, dim3(B_ * Q_),   dim3(64),  0, stream, cl, labels, cc);
        hipLaunchKernelGGL(mask_cost_mono_kernel, dim3(B_ * Q_), dim3(1024), 0, stream,
                           mq, ml, cc, lab_ps, cost);
        hipLaunchKernelGGL(hungarian_kernel,  dim3(B_), dim3(64), 0, stream, cost, out);
    }
}

// Round 15
// 107.901 us; speedup vs baseline: 4.4159x; 4.4159x over previous
//
#include <hip/hip_runtime.h>
#include <hip/hip_bf16.h>
#include <math.h>

#define HW_   65536
#define B_    2
#define Q_    100
#define C_    134
#define T_    20
#define NHUN  100
#define MT_   7            // M-tiles of 16 queries (112 >= 100)
#define KSB   128          // K-split blocks per (b,mt)
#define BKCH  512          // k per block
#define PREC  1088         // part record stride (1024 frag + 16 F + 16 P + pad)
#define CPAD  21           // padded cost row stride (floats) in hungarian LDS

typedef __attribute__((ext_vector_type(8))) short bf16x8;
typedef __attribute__((ext_vector_type(4))) float f32x4;

// ws layout (float units)
#define LABPS_OFF  0                    // [2][20][8]   (fallback path only)
#define CC_OFF     512                  // [200][20]    (fallback path only)
#define COST_OFF   4608                 // [200][20]    (fallback path only)
#define BASE_END   8704
#define PART_OFF   BASE_END                         // 1792 records * 1088 floats
#define CSUM_OFF   (PART_OFF + B_ * KSB * MT_ * PREC)   // 14*1056
#define WS_END_F   (CSUM_OFF + B_ * MT_ * 1056)

__device__ inline unsigned short f2bf(float f) {
    unsigned int u = __builtin_bit_cast(unsigned int, f);
    u += 0x7FFFu + ((u >> 16) & 1u);               // RNE
    return (unsigned short)(u >> 16);
}
__device__ inline float softplusf(float x) {
    float ax = fabsf(x);
    return fmaxf(x, 0.0f) + log1pf(expf(-ax));
}

// ---------------- K1: focal MFMA, direct-from-ml B operand (no lab_prep) ----------------
// blockIdx.x = (b*KSB + ks)*MT_ + mt ; 256 thr (4 waves, each 128 k).
// B fragments built inline from decimated ml (16 even floats = 4 float4 per frag).
// Ones-row trick: A-row q=100 (mt==6, lr==4) set to 1.0 -> C row 4 of mt 6 tile
// accumulates sum(lab) per t (exact lab row sums through the same MFMA path).
__global__ __launch_bounds__(256, 4) void focal_mfma_kernel(
        const float* __restrict__ mq, const float* __restrict__ ml,
        float* __restrict__ part) {
    int idx = blockIdx.x;
    int mt  = idx % MT_;
    int rem = idx / MT_;
    int ks  = rem % KSB;
    int b   = rem / KSB;
    int tid  = threadIdx.x;
    int wave = tid >> 6, lane = tid & 63;
    int lg = lane >> 4, lr = lane & 15;

    int q = mt * 16 + lr;
    bool qok = (q < Q_);
    const float* xrow = mq + ((size_t)(b * Q_ + (qok ? q : 0)) << 16);
    int koff = ks * BKCH + wave * 128 + lg * 8;

    const float* mlb1 = ml + ((size_t)(b * T_ + lr) << 18);            // plane = 262144 floats
    const float* mlb2 = ml + ((size_t)(b * T_ + 16 + (lr & 3)) << 18);
    bool n2row   = (lr < 4);
    bool onesrow = (mt == 6) && (lr == 4);

    f32x4 accD0 = {0,0,0,0}, accD1 = {0,0,0,0};
    f32x4 accP0 = {0,0,0,0}, accP1 = {0,0,0,0};
    float F = 0.f, P = 0.f;

    bf16x8 zer, one;
#pragma unroll
    for (int e = 0; e < 8; ++e) { zer[e] = 0; one[e] = (short)0x3F80; }

#pragma unroll
    for (int kk = 0; kk < 4; ++kk) {
        int kb = koff + kk * 32;             // decimated k base (mult of 8, row-contained)
        int r  = kb >> 8, c = kb & 255;
        int soff = r * 1024 + 2 * c;         // source float offset (even row 2r, col 2c)

        float4 u0 = *(const float4*)(xrow + kb);
        float4 u1 = *(const float4*)(xrow + kb + 4);
        float4 s0 = *(const float4*)(mlb1 + soff);
        float4 s1 = *(const float4*)(mlb1 + soff + 4);
        float4 s2 = *(const float4*)(mlb1 + soff + 8);
        float4 s3 = *(const float4*)(mlb1 + soff + 12);
        float4 t0 = *(const float4*)(mlb2 + soff);
        float4 t1 = *(const float4*)(mlb2 + soff + 4);
        float4 t2 = *(const float4*)(mlb2 + soff + 8);
        float4 t3 = *(const float4*)(mlb2 + soff + 12);

        bf16x8 f1, f2;
        f1[0] = (short)f2bf(s0.x); f1[1] = (short)f2bf(s0.z);
        f1[2] = (short)f2bf(s1.x); f1[3] = (short)f2bf(s1.z);
        f1[4] = (short)f2bf(s2.x); f1[5] = (short)f2bf(s2.z);
        f1[6] = (short)f2bf(s3.x); f1[7] = (short)f2bf(s3.z);
        if (n2row) {
            f2[0] = (short)f2bf(t0.x); f2[1] = (short)f2bf(t0.z);
            f2[2] = (short)f2bf(t1.x); f2[3] = (short)f2bf(t1.z);
            f2[4] = (short)f2bf(t2.x); f2[5] = (short)f2bf(t2.z);
            f2[6] = (short)f2bf(t3.x); f2[7] = (short)f2bf(t3.z);
        } else {
            f2 = zer;
        }

        float xv[8] = {u0.x, u0.y, u0.z, u0.w, u1.x, u1.y, u1.z, u1.w};
        bf16x8 dh, ph;
#pragma unroll
        for (int e = 0; e < 8; ++e) {
            float x  = xv[e];
            float ax = fabsf(x);
            float a  = __expf(-ax);
            float rr = 1.0f / (1.0f + a);
            float p  = (x >= 0.f) ? rr : a * rr;
            float om = (x >= 0.f) ? a * rr : rr;
            float l1 = __logf(1.0f + a);
            float spn = fmaxf(-x, 0.f) + l1;       // softplus(-x)
            float spp = spn + x;                   // softplus(x)
            float fp = 0.25f * om * om * spn;
            float fn = 0.75f * p * p * spp;
            F += fn; P += p;
            dh[e] = (short)f2bf(fp - fn);
            ph[e] = (short)f2bf(p);
        }
        if (onesrow) { dh = one; ph = one; }

        accD0 = __builtin_amdgcn_mfma_f32_16x16x32_bf16(dh, f1, accD0, 0, 0, 0);
        accD1 = __builtin_amdgcn_mfma_f32_16x16x32_bf16(dh, f2, accD1, 0, 0, 0);
        accP0 = __builtin_amdgcn_mfma_f32_16x16x32_bf16(ph, f1, accP0, 0, 0, 0);
        accP1 = __builtin_amdgcn_mfma_f32_16x16x32_bf16(ph, f2, accP1, 0, 0, 0);
    }

    F += __shfl_down(F, 32); F += __shfl_down(F, 16);
    P += __shfl_down(P, 32); P += __shfl_down(P, 16);

    __shared__ float red[4][4][64][4];
    __shared__ float fpb[4][2][16];
#pragma unroll
    for (int r = 0; r < 4; ++r) {
        red[wave][0][lane][r] = accD0[r];
        red[wave][1][lane][r] = accD1[r];
        red[wave][2][lane][r] = accP0[r];
        red[wave][3][lane][r] = accP1[r];
    }
    if (lane < 16) { fpb[wave][0][lane] = F; fpb[wave][1][lane] = P; }
    __syncthreads();
    {
        int e4 = tid;                      // 256 float4 groups = 1024 floats
        int f  = e4 >> 6;
        int l2 = e4 & 63;
        float4 s;
        s.x = red[0][f][l2][0] + red[1][f][l2][0] + red[2][f][l2][0] + red[3][f][l2][0];
        s.y = red[0][f][l2][1] + red[1][f][l2][1] + red[2][f][l2][1] + red[3][f][l2][1];
        s.z = red[0][f][l2][2] + red[1][f][l2][2] + red[2][f][l2][2] + red[3][f][l2][2];
        s.w = red[0][f][l2][3] + red[1][f][l2][3] + red[2][f][l2][3] + red[3][f][l2][3];
        *(float4*)(part + (size_t)idx * PREC + e4 * 4) = s;
    }
    if (tid < 16)
        part[(size_t)idx * PREC + 1024 + tid] =
            fpb[0][0][tid] + fpb[1][0][tid] + fpb[2][0][tid] + fpb[3][0][tid];
    else if (tid < 32) {
        int l = tid - 16;
        part[(size_t)idx * PREC + 1040 + l] =
            fpb[0][1][l] + fpb[1][1][l] + fpb[2][1][l] + fpb[3][1][l];
    }
}

// ---------------- K2: parallel K-split reduction: part -> Csum[14][1056] ----------------
__global__ __launch_bounds__(256) void reduce_part_kernel(const float* __restrict__ part,
                                                          float* __restrict__ Csum) {
    int bm   = blockIdx.x;          // 0..13
    int mt   = bm % MT_;
    int b    = bm / MT_;
    int tid  = threadIdx.x;
    int epos = tid & 31;
    int grp  = tid >> 5;            // 0..7
    int e    = blockIdx.y * 32 + epos;   // 0..1055

    const float* base = part + (size_t)((b * KSB) * MT_ + mt) * PREC + e;
    float s = 0.f;
    for (int k = 0; k < 16; ++k)
        s += base[(size_t)(grp * 16 + k) * MT_ * PREC];
    __shared__ float red[8][33];
    red[grp][epos] = s;
    __syncthreads();
    if (tid < 32) {
        float tot = 0.f;
        for (int g = 0; g < 8; ++g) tot += red[g][tid];
        Csum[(size_t)bm * 1056 + e] = tot;
    }
}

// ---------------- K3: fused compose + greedy register JV Hungarian ----------------
// grid B_, 256 thr. fused=1: build cost in LDS from Csum + class-softmax + ones-row L.
// fused=0 (fallback): read cost[] from global. Wave 0 then runs the R12-proven solver.
__global__ __launch_bounds__(256) void hungarian_kernel(
        const float* __restrict__ Csum, const float* __restrict__ cl,
        const int* __restrict__ labels_g, const float* __restrict__ cost_g,
        int* __restrict__ out, int fused) {
    int b   = blockIdx.x;
    int tid = threadIdx.x;

    __shared__ float csh[Q_ * CPAD];
    __shared__ int   psh[NHUN + 1];
    __shared__ float Lt[T_];
    __shared__ int   lbl[T_];

    if (fused) {
        if (tid < T_) {
            lbl[tid] = labels_g[b * T_ + tid];
            // L[t] = ones-row (qm=4) of the mt=6 tile, quantity P, reg 0
            const float* CL = Csum + (size_t)(b * MT_ + 6) * 1056;
            int nt = tid >> 4;
            int ln = 16 + (tid & 15);          // ((4>>2)<<4) | (t&15)
            Lt[tid] = CL[(2 + nt) * 256 + ln * 4];
        }
        __syncthreads();
        if (tid < Q_) {
            int q = tid, mt = q >> 4, qm = q & 15;
            const float* C   = Csum + (size_t)(b * MT_ + mt) * 1056;
            const float* row = cl + (size_t)(b * Q_ + q) * C_;
            float m = -INFINITY;
            for (int c = 0; c < C_; ++c) m = fmaxf(m, row[c]);
            float s = 0.f;
            for (int c = 0; c < C_; ++c) s += expf(row[c] - m);
            float F = C[1024 + qm];
            float P = C[1040 + qm];
#pragma unroll
            for (int t = 0; t < T_; ++t) {
                int nt = t >> 4;
                int ln = ((qm >> 2) << 4) | (t & 15);
                int rg = qm & 3;
                float Sd = C[(0 + nt) * 256 + ln * 4 + rg];
                float Sp = C[(2 + nt) * 256 + ln * 4 + rg];
                float ccv = -expf(row[lbl[t]] - m) / s;
                float cm = (Sd + F) * (1.0f / (float)HW_);
                float cd = 1.0f - (2.0f * Sp + 1.0f) / (P + Lt[t] + 1.0f);
                csh[q * CPAD + t] = cm + cd + ccv;
            }
        }
    } else {
        for (int idx = tid; idx < Q_ * T_; idx += 256) {
            int q = idx / T_, t = idx % T_;
            csh[q * CPAD + t] = cost_g[b * Q_ * T_ + idx];
        }
    }
    __syncthreads();

    if (tid < 64) {
        int lane = tid;
        const int ja = lane;                 // 0 = virtual root
        const int jb = lane + 64;
        const bool ja_ok = (ja >= 1);
        const bool jb_ok = (jb <= NHUN);

        int   p_a = 0, p_b = 0;
        float v_a = 0.f, v_b = 0.f;
        float u_reg = 0.f;

        // greedy init: u[i] = row min; assign to argmin col if free
        for (int i = 1; i <= T_; ++i) {
            float ca = ja_ok ? csh[(ja - 1) * CPAD + (i - 1)] : INFINITY;
            float cb = jb_ok ? csh[(jb - 1) * CPAD + (i - 1)] : INFINITY;
            float vmin = fminf(ca, cb);
            for (int off = 32; off > 0; off >>= 1)
                vmin = fminf(vmin, __shfl_xor(vmin, off));
            unsigned long long ba = __ballot(ca == vmin);
            int j1 = ba ? (__ffsll(ba) - 1) : (__ffsll(__ballot(cb == vmin)) - 1 + 64);
            if (lane == i) u_reg = vmin;
            int pj = __shfl((j1 < 64) ? p_a : p_b, j1 & 63);
            if (pj == 0) {
                if (j1 < 64) { if (lane == j1) p_a = i; }
                else         { if (lane == j1 - 64) p_b = i; }
            }
        }

        // Dijkstra phases for leftover rows
        for (int i = 1; i <= T_; ++i) {
            bool mine = (p_a == i) || (p_b == i);
            if (__ballot(mine)) continue;

            float m_a = INFINITY, m_b = INFINITY;
            int   way_a = 0, way_b = 0;
            bool  us_a = false, us_b = false;
            bool  in_tree = (lane == i);
            int   j0 = 0, jf;

            while (true) {
                int i0 = (j0 == 0) ? i : __shfl((j0 < 64) ? p_a : p_b, j0 & 63);
                if (lane == i0) in_tree = true;
                float ui0 = __shfl(u_reg, i0);
                if (ja == j0) us_a = true;
                if (jb == j0) us_b = true;
                bool fa = ja_ok && !us_a;
                bool fb = jb_ok && !us_b;
                if (fa) {
                    float cur = csh[(ja - 1) * CPAD + (i0 - 1)] - ui0 - v_a;
                    if (cur < m_a) { m_a = cur; way_a = j0; }
                }
                if (fb) {
                    float cur = csh[(jb - 1) * CPAD + (i0 - 1)] - ui0 - v_b;
                    if (cur < m_b) { m_b = cur; way_b = j0; }
                }
                float ca = fa ? m_a : INFINITY;
                float cb = fb ? m_b : INFINITY;
                float vmin = fminf(ca, cb);
                for (int off = 32; off > 0; off >>= 1)
                    vmin = fminf(vmin, __shfl_xor(vmin, off));
                unsigned long long ba = __ballot(ca == vmin);
                int j1 = ba ? (__ffsll(ba) - 1) : (__ffsll(__ballot(cb == vmin)) - 1 + 64);
                float delta = vmin;
                if (us_a) v_a -= delta; else m_a -= delta;
                if (us_b) v_b -= delta; else m_b -= delta;
                if (in_tree) u_reg += delta;
                j0 = j1;
                int pj0 = __shfl((j0 < 64) ? p_a : p_b, j0 & 63);
                if (pj0 == 0) { jf = j0; break; }
            }
            int jj = jf;
            while (jj) {
                int wv = __shfl((jj < 64) ? way_a : way_b, jj & 63);
                int pn = (wv == 0) ? i : __shfl((wv < 64) ? p_a : p_b, wv & 63);
                if (jj < 64) { if (lane == jj) p_a = pn; }
                else         { if (lane == jj - 64) p_b = pn; }
                jj = wv;
            }
        }

        if (ja_ok) psh[ja] = p_a;
        if (jb_ok) psh[jb] = p_b;
        if (lane == 0) psh[0] = 0;
    }
    __syncthreads();
    if (tid == 0) {
        int* ob = out + b * 2 * T_;
        int k = 0;
        for (int j = 1; j <= NHUN; ++j) {
            if (psh[j] != 0) { ob[k] = j - 1; ob[T_ + k] = psh[j] - 1; ++k; }
        }
    }
}

// ==================== fallback path (small ws): round-2-proven kernels ====================
__global__ void lab_prep_kernel(const float* __restrict__ ml, float* __restrict__ lab_ps) {
    int b = blockIdx.x, t = blockIdx.y, ksl = blockIdx.z;
    int tid = threadIdx.x;
    const float* src = ml + (size_t)(b * T_ + t) * 262144;
    float acc = 0.f;
    for (int it = 0; it < 8; ++it) {
        int k = ksl * 8192 + it * 1024 + tid * 4;
        int r = k >> 8, c = k & 255;
        const float* s = src + r * 1024 + 2 * c;
        float4 u = *(const float4*)s;
        float4 w = *(const float4*)(s + 4);
        acc += u.x + u.z + w.x + w.z;
    }
    for (int off = 32; off > 0; off >>= 1) acc += __shfl_down(acc, off);
    __shared__ float sb[4];
    int wid = tid >> 6, lane = tid & 63;
    if (lane == 0) sb[wid] = acc;
    __syncthreads();
    if (tid == 0) lab_ps[(b * T_ + t) * 8 + ksl] = sb[0] + sb[1] + sb[2] + sb[3];
}

__global__ void class_cost_kernel(const float* __restrict__ cl, const int* __restrict__ labels,
                                  float* __restrict__ cc) {
    int bq  = blockIdx.x;
    int b   = bq / Q_;
    int tid = threadIdx.x;
    __shared__ float sl[C_];
    const float* src = cl + (size_t)bq * C_;
    for (int c = tid; c < C_; c += 64) sl[c] = src[c];
    __syncthreads();
    float mx = -INFINITY;
    for (int c = tid; c < C_; c += 64) mx = fmaxf(mx, sl[c]);
    for (int off = 32; off > 0; off >>= 1) mx = fmaxf(mx, __shfl_xor(mx, off));
    float se = 0.f;
    for (int c = tid; c < C_; c += 64) se += expf(sl[c] - mx);
    for (int off = 32; off > 0; off >>= 1) se += __shfl_xor(se, off);
    float inv = 1.0f / se;
    if (tid < T_) {
        int lbl = labels[b * T_ + tid];
        cc[bq * T_ + tid] = -expf(sl[lbl] - mx) * inv;
    }
}

__global__ __launch_bounds__(1024) void mask_cost_mono_kernel(
        const float* __restrict__ mq, const float* __restrict__ ml,
        const float* __restrict__ cc, const float* __restrict__ lab_ps,
        float* __restrict__ cost) {
    int bq  = blockIdx.x;
    int b   = bq / Q_;
    int tid = threadIdx.x;
    const float* xb  = mq + (size_t)bq * HW_;
    const float* mlb = ml + (size_t)b * T_ * 262144;
    float s1[T_], s2[T_];
#pragma unroll
    for (int t = 0; t < T_; ++t) { s1[t] = 0.f; s2[t] = 0.f; }
    float F = 0.f, P = 0.f;
    for (int k = tid; k < HW_; k += 1024) {
        int i = k >> 8, j = k & 255;
        float x = xb[k];
        float p = 1.0f / (1.0f + expf(-x));
        float spn = softplusf(-x);
        float spp = softplusf(x);
        float om = 1.0f - p;
        float fp = 0.25f * om * om * spn;
        float fn = 0.75f * p * p * spp;
        F += fn; P += p;
        float diff = fp - fn;
        int off0 = i * 1024 + 2 * j;
#pragma unroll
        for (int t = 0; t < T_; ++t) {
            float lab = mlb[t * 262144 + off0];
            s1[t] = fmaf(diff, lab, s1[t]);
            s2[t] = fmaf(p,    lab, s2[t]);
        }
    }
    __shared__ float sbuf[16][42];
    int wid = tid >> 6, lane = tid & 63;
#pragma unroll
    for (int t = 0; t < T_; ++t) {
        for (int off = 32; off > 0; off >>= 1) {
            s1[t] += __shfl_down(s1[t], off);
            s2[t] += __shfl_down(s2[t], off);
        }
    }
    for (int off = 32; off > 0; off >>= 1) { F += __shfl_down(F, off); P += __shfl_down(P, off); }
    if (lane == 0) {
#pragma unroll
        for (int t = 0; t < T_; ++t) { sbuf[wid][t] = s1[t]; sbuf[wid][T_ + t] = s2[t]; }
        sbuf[wid][40] = F; sbuf[wid][41] = P;
    }
    __syncthreads();
    if (tid < T_) {
        float S1 = 0.f, S2 = 0.f, Fs = 0.f, Ps = 0.f;
        for (int w = 0; w < 16; ++w) {
            S1 += sbuf[w][tid]; S2 += sbuf[w][T_ + tid];
            Fs += sbuf[w][40];  Ps += sbuf[w][41];
        }
        float L = 0.f;
        for (int sl = 0; sl < 8; ++sl) L += lab_ps[(b * T_ + tid) * 8 + sl];
        float cm = (S1 + Fs) * (1.0f / (float)HW_);
        float cd = 1.0f - (2.0f * S2 + 1.0f) / (Ps + L + 1.0f);
        cost[bq * T_ + tid] = cm + cd + cc[bq * T_ + tid];
    }
}

extern "C" void kernel_launch(void* const* d_in, const int* in_sizes, int n_in,
                              void* d_out, int out_size, void* d_ws, size_t ws_size,
                              hipStream_t stream) {
    const float* mq     = (const float*)d_in[0];   // [2,100,256,256]
    const float* cl     = (const float*)d_in[1];   // [2,100,134]
    const float* ml     = (const float*)d_in[2];   // [2,20,512,512]
    const int*   labels = (const int*)d_in[3];     // [2,20]
    int* out = (int*)d_out;                        // [2,2,20] int32
    float* ws = (float*)d_ws;

    float* lab_ps = ws + LABPS_OFF;
    float* cc     = ws + CC_OFF;
    float* cost   = ws + COST_OFF;

    size_t need = (size_t)WS_END_F * 4;

    if (ws_size >= need) {
        float* part = ws + PART_OFF;
        float* Csum = ws + CSUM_OFF;
        hipLaunchKernelGGL(focal_mfma_kernel,  dim3(B_ * KSB * MT_), dim3(256), 0, stream,
                           mq, ml, part);
        hipLaunchKernelGGL(reduce_part_kernel, dim3(B_ * MT_, 33), dim3(256), 0, stream,
                           part, Csum);
        hipLaunchKernelGGL(hungarian_kernel,   dim3(B_), dim3(256), 0, stream,
                           Csum, cl, labels, cost, out, 1);
    } else {
        hipLaunchKernelGGL(lab_prep_kernel,    dim3(B_, T_, 8), dim3(256), 0, stream,
                           ml, lab_ps);
        hipLaunchKernelGGL(class_cost_kernel,  dim3(B_ * Q_), dim3(64), 0, stream,
                           cl, labels, cc);
        hipLaunchKernelGGL(mask_cost_mono_kernel, dim3(B_ * Q_), dim3(1024), 0, stream,
                           mq, ml, cc, lab_ps, cost);
        hipLaunchKernelGGL(hungarian_kernel,   dim3(B_), dim3(256), 0, stream,
                           ws, cl, labels, cost, out, 0);
    }
}

// Round 16
// 95.218 us; speedup vs baseline: 5.0041x; 1.1332x over previous
//
#include <hip/hip_runtime.h>
#include <hip/hip_bf16.h>
#include <math.h>

#define HW_   65536
#define B_    2
#define Q_    100
#define C_    134
#define T_    20
#define NHUN  100
#define MT_   7            // M-tiles of 16 queries (112 >= 100)
#define KSB   128          // K-split blocks per (b,mt)
#define BKCH  512          // k per block
#define PREC  1088         // part record stride (1024 frag + 16 F + 16 P + pad)
#define CPAD  21           // padded cost row stride (floats) in hungarian LDS
#define CLP   136          // padded class-logits row stride (floats)

typedef __attribute__((ext_vector_type(8))) short bf16x8;
typedef __attribute__((ext_vector_type(4))) float f32x4;

// ws layout (float units)
#define LABPS_OFF  0                    // [2][20][8]   (fallback path only)
#define CC_OFF     512                  // [200][20]    (fallback path only)
#define COST_OFF   4608                 // [200][20]    (fallback path only)
#define BASE_END   8704
#define PART_OFF   BASE_END                         // 1792 records * 1088 floats
#define CSUM_OFF   (PART_OFF + B_ * KSB * MT_ * PREC)   // 14*1056
#define WS_END_F   (CSUM_OFF + B_ * MT_ * 1056)

__device__ inline unsigned short f2bf(float f) {
    unsigned int u = __builtin_bit_cast(unsigned int, f);
    u += 0x7FFFu + ((u >> 16) & 1u);               // RNE
    return (unsigned short)(u >> 16);
}
__device__ inline float softplusf(float x) {
    float ax = fabsf(x);
    return fmaxf(x, 0.0f) + log1pf(expf(-ax));
}

// ---------------- K1: focal MFMA, direct-from-ml B operand (R15-proven) ----------------
__global__ __launch_bounds__(256, 4) void focal_mfma_kernel(
        const float* __restrict__ mq, const float* __restrict__ ml,
        float* __restrict__ part) {
    int idx = blockIdx.x;
    int mt  = idx % MT_;
    int rem = idx / MT_;
    int ks  = rem % KSB;
    int b   = rem / KSB;
    int tid  = threadIdx.x;
    int wave = tid >> 6, lane = tid & 63;
    int lg = lane >> 4, lr = lane & 15;

    int q = mt * 16 + lr;
    bool qok = (q < Q_);
    const float* xrow = mq + ((size_t)(b * Q_ + (qok ? q : 0)) << 16);
    int koff = ks * BKCH + wave * 128 + lg * 8;

    const float* mlb1 = ml + ((size_t)(b * T_ + lr) << 18);
    const float* mlb2 = ml + ((size_t)(b * T_ + 16 + (lr & 3)) << 18);
    bool n2row   = (lr < 4);
    bool onesrow = (mt == 6) && (lr == 4);

    f32x4 accD0 = {0,0,0,0}, accD1 = {0,0,0,0};
    f32x4 accP0 = {0,0,0,0}, accP1 = {0,0,0,0};
    float F = 0.f, P = 0.f;

    bf16x8 zer, one;
#pragma unroll
    for (int e = 0; e < 8; ++e) { zer[e] = 0; one[e] = (short)0x3F80; }

#pragma unroll
    for (int kk = 0; kk < 4; ++kk) {
        int kb = koff + kk * 32;
        int r  = kb >> 8, c = kb & 255;
        int soff = r * 1024 + 2 * c;

        float4 u0 = *(const float4*)(xrow + kb);
        float4 u1 = *(const float4*)(xrow + kb + 4);
        float4 s0 = *(const float4*)(mlb1 + soff);
        float4 s1 = *(const float4*)(mlb1 + soff + 4);
        float4 s2 = *(const float4*)(mlb1 + soff + 8);
        float4 s3 = *(const float4*)(mlb1 + soff + 12);
        float4 t0 = *(const float4*)(mlb2 + soff);
        float4 t1 = *(const float4*)(mlb2 + soff + 4);
        float4 t2 = *(const float4*)(mlb2 + soff + 8);
        float4 t3 = *(const float4*)(mlb2 + soff + 12);

        bf16x8 f1, f2;
        f1[0] = (short)f2bf(s0.x); f1[1] = (short)f2bf(s0.z);
        f1[2] = (short)f2bf(s1.x); f1[3] = (short)f2bf(s1.z);
        f1[4] = (short)f2bf(s2.x); f1[5] = (short)f2bf(s2.z);
        f1[6] = (short)f2bf(s3.x); f1[7] = (short)f2bf(s3.z);
        if (n2row) {
            f2[0] = (short)f2bf(t0.x); f2[1] = (short)f2bf(t0.z);
            f2[2] = (short)f2bf(t1.x); f2[3] = (short)f2bf(t1.z);
            f2[4] = (short)f2bf(t2.x); f2[5] = (short)f2bf(t2.z);
            f2[6] = (short)f2bf(t3.x); f2[7] = (short)f2bf(t3.z);
        } else {
            f2 = zer;
        }

        float xv[8] = {u0.x, u0.y, u0.z, u0.w, u1.x, u1.y, u1.z, u1.w};
        bf16x8 dh, ph;
#pragma unroll
        for (int e = 0; e < 8; ++e) {
            float x  = xv[e];
            float ax = fabsf(x);
            float a  = __expf(-ax);
            float rr = 1.0f / (1.0f + a);
            float p  = (x >= 0.f) ? rr : a * rr;
            float om = (x >= 0.f) ? a * rr : rr;
            float l1 = __logf(1.0f + a);
            float spn = fmaxf(-x, 0.f) + l1;
            float spp = spn + x;
            float fp = 0.25f * om * om * spn;
            float fn = 0.75f * p * p * spp;
            F += fn; P += p;
            dh[e] = (short)f2bf(fp - fn);
            ph[e] = (short)f2bf(p);
        }
        if (onesrow) { dh = one; ph = one; }

        accD0 = __builtin_amdgcn_mfma_f32_16x16x32_bf16(dh, f1, accD0, 0, 0, 0);
        accD1 = __builtin_amdgcn_mfma_f32_16x16x32_bf16(dh, f2, accD1, 0, 0, 0);
        accP0 = __builtin_amdgcn_mfma_f32_16x16x32_bf16(ph, f1, accP0, 0, 0, 0);
        accP1 = __builtin_amdgcn_mfma_f32_16x16x32_bf16(ph, f2, accP1, 0, 0, 0);
    }

    F += __shfl_down(F, 32); F += __shfl_down(F, 16);
    P += __shfl_down(P, 32); P += __shfl_down(P, 16);

    __shared__ float red[4][4][64][4];
    __shared__ float fpb[4][2][16];
#pragma unroll
    for (int r = 0; r < 4; ++r) {
        red[wave][0][lane][r] = accD0[r];
        red[wave][1][lane][r] = accD1[r];
        red[wave][2][lane][r] = accP0[r];
        red[wave][3][lane][r] = accP1[r];
    }
    if (lane < 16) { fpb[wave][0][lane] = F; fpb[wave][1][lane] = P; }
    __syncthreads();
    {
        int e4 = tid;
        int f  = e4 >> 6;
        int l2 = e4 & 63;
        float4 s;
        s.x = red[0][f][l2][0] + red[1][f][l2][0] + red[2][f][l2][0] + red[3][f][l2][0];
        s.y = red[0][f][l2][1] + red[1][f][l2][1] + red[2][f][l2][1] + red[3][f][l2][1];
        s.z = red[0][f][l2][2] + red[1][f][l2][2] + red[2][f][l2][2] + red[3][f][l2][2];
        s.w = red[0][f][l2][3] + red[1][f][l2][3] + red[2][f][l2][3] + red[3][f][l2][3];
        *(float4*)(part + (size_t)idx * PREC + e4 * 4) = s;
    }
    if (tid < 16)
        part[(size_t)idx * PREC + 1024 + tid] =
            fpb[0][0][tid] + fpb[1][0][tid] + fpb[2][0][tid] + fpb[3][0][tid];
    else if (tid < 32) {
        int l = tid - 16;
        part[(size_t)idx * PREC + 1040 + l] =
            fpb[0][1][l] + fpb[1][1][l] + fpb[2][1][l] + fpb[3][1][l];
    }
}

// ---------------- K2: parallel K-split reduction: part -> Csum[14][1056] ----------------
__global__ __launch_bounds__(256) void reduce_part_kernel(const float* __restrict__ part,
                                                          float* __restrict__ Csum) {
    int bm   = blockIdx.x;          // 0..13
    int mt   = bm % MT_;
    int b    = bm / MT_;
    int tid  = threadIdx.x;
    int epos = tid & 31;
    int grp  = tid >> 5;            // 0..7
    int e    = blockIdx.y * 32 + epos;   // 0..1055

    const float* base = part + (size_t)((b * KSB) * MT_ + mt) * PREC + e;
    float s = 0.f;
    for (int k = 0; k < 16; ++k)
        s += base[(size_t)(grp * 16 + k) * MT_ * PREC];
    __shared__ float red[8][33];
    red[grp][epos] = s;
    __syncthreads();
    if (tid < 32) {
        float tot = 0.f;
        for (int g = 0; g < 8; ++g) tot += red[g][tid];
        Csum[(size_t)bm * 1056 + e] = tot;
    }
}

// ---------------- K3: fused compose (LDS-staged cl) + greedy register JV Hungarian ----------------
// grid B_, 256 thr. fused=1: stage cl rows in LDS (coalesced), per-thread softmax from
// LDS float4, build cost in csh; fused=0: read cost_g. Wave 0 runs the R12-proven solver.
__global__ __launch_bounds__(256) void hungarian_kernel(
        const float* __restrict__ Csum, const float* __restrict__ cl,
        const int* __restrict__ labels_g, const float* __restrict__ cost_g,
        int* __restrict__ out, int fused) {
    int b   = blockIdx.x;
    int tid = threadIdx.x;

    __shared__ float sl[Q_ * CLP];       // 54,400 B
    __shared__ float csh[Q_ * CPAD];     //  8,400 B
    __shared__ int   psh[NHUN + 1];
    __shared__ float Lt[T_];
    __shared__ int   lbl[T_];

    if (fused) {
        // cooperative coalesced staging of class logits (pad with -INF)
        for (int idx = tid; idx < Q_ * CLP; idx += 256) {
            int q = idx / CLP, c = idx % CLP;
            sl[idx] = (c < C_) ? cl[(size_t)(b * Q_ + q) * C_ + c] : -INFINITY;
        }
        if (tid < T_) {
            lbl[tid] = labels_g[b * T_ + tid];
            // L[t] = ones-row (qm=4) of the mt=6 tile, quantity P, reg 0
            const float* CL = Csum + (size_t)(b * MT_ + 6) * 1056;
            int nt = tid >> 4;
            int ln = 16 + (tid & 15);
            Lt[tid] = CL[(2 + nt) * 256 + ln * 4];
        }
        __syncthreads();
        if (tid < Q_) {
            int q = tid, mt = q >> 4, qm = q & 15;
            const float* C  = Csum + (size_t)(b * MT_ + mt) * 1056;
            const float4* r4 = (const float4*)(sl + q * CLP);
            float m = -INFINITY;
#pragma unroll
            for (int c4 = 0; c4 < CLP / 4; ++c4) {
                float4 v = r4[c4];
                m = fmaxf(m, fmaxf(fmaxf(v.x, v.y), fmaxf(v.z, v.w)));
            }
            float s = 0.f;
#pragma unroll
            for (int c4 = 0; c4 < CLP / 4; ++c4) {
                float4 v = r4[c4];
                s += expf(v.x - m) + expf(v.y - m) + expf(v.z - m) + expf(v.w - m);
            }
            float F = C[1024 + qm];
            float P = C[1040 + qm];
#pragma unroll
            for (int t = 0; t < T_; ++t) {
                int nt = t >> 4;
                int ln = ((qm >> 2) << 4) | (t & 15);
                int rg = qm & 3;
                float Sd = C[(0 + nt) * 256 + ln * 4 + rg];
                float Sp = C[(2 + nt) * 256 + ln * 4 + rg];
                float ccv = -expf(sl[q * CLP + lbl[t]] - m) / s;
                float cm = (Sd + F) * (1.0f / (float)HW_);
                float cd = 1.0f - (2.0f * Sp + 1.0f) / (P + Lt[t] + 1.0f);
                csh[q * CPAD + t] = cm + cd + ccv;
            }
        }
    } else {
        for (int idx = tid; idx < Q_ * T_; idx += 256) {
            int q = idx / T_, t = idx % T_;
            csh[q * CPAD + t] = cost_g[b * Q_ * T_ + idx];
        }
    }
    __syncthreads();

    if (tid < 64) {
        int lane = tid;
        const int ja = lane;                 // 0 = virtual root
        const int jb = lane + 64;
        const bool ja_ok = (ja >= 1);
        const bool jb_ok = (jb <= NHUN);

        int   p_a = 0, p_b = 0;
        float v_a = 0.f, v_b = 0.f;
        float u_reg = 0.f;

        // greedy init: u[i] = row min; assign to argmin col if free
        for (int i = 1; i <= T_; ++i) {
            float ca = ja_ok ? csh[(ja - 1) * CPAD + (i - 1)] : INFINITY;
            float cb = jb_ok ? csh[(jb - 1) * CPAD + (i - 1)] : INFINITY;
            float vmin = fminf(ca, cb);
            for (int off = 32; off > 0; off >>= 1)
                vmin = fminf(vmin, __shfl_xor(vmin, off));
            unsigned long long ba = __ballot(ca == vmin);
            int j1 = ba ? (__ffsll(ba) - 1) : (__ffsll(__ballot(cb == vmin)) - 1 + 64);
            if (lane == i) u_reg = vmin;
            int pj = __shfl((j1 < 64) ? p_a : p_b, j1 & 63);
            if (pj == 0) {
                if (j1 < 64) { if (lane == j1) p_a = i; }
                else         { if (lane == j1 - 64) p_b = i; }
            }
        }

        // Dijkstra phases for leftover rows
        for (int i = 1; i <= T_; ++i) {
            bool mine = (p_a == i) || (p_b == i);
            if (__ballot(mine)) continue;

            float m_a = INFINITY, m_b = INFINITY;
            int   way_a = 0, way_b = 0;
            bool  us_a = false, us_b = false;
            bool  in_tree = (lane == i);
            int   j0 = 0, jf;

            while (true) {
                int i0 = (j0 == 0) ? i : __shfl((j0 < 64) ? p_a : p_b, j0 & 63);
                if (lane == i0) in_tree = true;
                float ui0 = __shfl(u_reg, i0);
                if (ja == j0) us_a = true;
                if (jb == j0) us_b = true;
                bool fa = ja_ok && !us_a;
                bool fb = jb_ok && !us_b;
                if (fa) {
                    float cur = csh[(ja - 1) * CPAD + (i0 - 1)] - ui0 - v_a;
                    if (cur < m_a) { m_a = cur; way_a = j0; }
                }
                if (fb) {
                    float cur = csh[(jb - 1) * CPAD + (i0 - 1)] - ui0 - v_b;
                    if (cur < m_b) { m_b = cur; way_b = j0; }
                }
                float ca = fa ? m_a : INFINITY;
                float cb = fb ? m_b : INFINITY;
                float vmin = fminf(ca, cb);
                for (int off = 32; off > 0; off >>= 1)
                    vmin = fminf(vmin, __shfl_xor(vmin, off));
                unsigned long long ba = __ballot(ca == vmin);
                int j1 = ba ? (__ffsll(ba) - 1) : (__ffsll(__ballot(cb == vmin)) - 1 + 64);
                float delta = vmin;
                if (us_a) v_a -= delta; else m_a -= delta;
                if (us_b) v_b -= delta; else m_b -= delta;
                if (in_tree) u_reg += delta;
                j0 = j1;
                int pj0 = __shfl((j0 < 64) ? p_a : p_b, j0 & 63);
                if (pj0 == 0) { jf = j0; break; }
            }
            int jj = jf;
            while (jj) {
                int wv = __shfl((jj < 64) ? way_a : way_b, jj & 63);
                int pn = (wv == 0) ? i : __shfl((wv < 64) ? p_a : p_b, wv & 63);
                if (jj < 64) { if (lane == jj) p_a = pn; }
                else         { if (lane == jj - 64) p_b = pn; }
                jj = wv;
            }
        }

        if (ja_ok) psh[ja] = p_a;
        if (jb_ok) psh[jb] = p_b;
        if (lane == 0) psh[0] = 0;
    }
    __syncthreads();
    if (tid == 0) {
        int* ob = out + b * 2 * T_;
        int k = 0;
        for (int j = 1; j <= NHUN; ++j) {
            if (psh[j] != 0) { ob[k] = j - 1; ob[T_ + k] = psh[j] - 1; ++k; }
        }
    }
}

// ==================== fallback path (small ws): round-2-proven kernels ====================
__global__ void lab_prep_kernel(const float* __restrict__ ml, float* __restrict__ lab_ps) {
    int b = blockIdx.x, t = blockIdx.y, ksl = blockIdx.z;
    int tid = threadIdx.x;
    const float* src = ml + (size_t)(b * T_ + t) * 262144;
    float acc = 0.f;
    for (int it = 0; it < 8; ++it) {
        int k = ksl * 8192 + it * 1024 + tid * 4;
        int r = k >> 8, c = k & 255;
        const float* s = src + r * 1024 + 2 * c;
        float4 u = *(const float4*)s;
        float4 w = *(const float4*)(s + 4);
        acc += u.x + u.z + w.x + w.z;
    }
    for (int off = 32; off > 0; off >>= 1) acc += __shfl_down(acc, off);
    __shared__ float sb[4];
    int wid = tid >> 6, lane = tid & 63;
    if (lane == 0) sb[wid] = acc;
    __syncthreads();
    if (tid == 0) lab_ps[(b * T_ + t) * 8 + ksl] = sb[0] + sb[1] + sb[2] + sb[3];
}

__global__ void class_cost_kernel(const float* __restrict__ cl, const int* __restrict__ labels,
                                  float* __restrict__ cc) {
    int bq  = blockIdx.x;
    int b   = bq / Q_;
    int tid = threadIdx.x;
    __shared__ float sl[C_];
    const float* src = cl + (size_t)bq * C_;
    for (int c = tid; c < C_; c += 64) sl[c] = src[c];
    __syncthreads();
    float mx = -INFINITY;
    for (int c = tid; c < C_; c += 64) mx = fmaxf(mx, sl[c]);
    for (int off = 32; off > 0; off >>= 1) mx = fmaxf(mx, __shfl_xor(mx, off));
    float se = 0.f;
    for (int c = tid; c < C_; c += 64) se += expf(sl[c] - mx);
    for (int off = 32; off > 0; off >>= 1) se += __shfl_xor(se, off);
    float inv = 1.0f / se;
    if (tid < T_) {
        int lbl = labels[b * T_ + tid];
        cc[bq * T_ + tid] = -expf(sl[lbl] - mx) * inv;
    }
}

__global__ __launch_bounds__(1024) void mask_cost_mono_kernel(
        const float* __restrict__ mq, const float* __restrict__ ml,
        const float* __restrict__ cc, const float* __restrict__ lab_ps,
        float* __restrict__ cost) {
    int bq  = blockIdx.x;
    int b   = bq / Q_;
    int tid = threadIdx.x;
    const float* xb  = mq + (size_t)bq * HW_;
    const float* mlb = ml + (size_t)b * T_ * 262144;
    float s1[T_], s2[T_];
#pragma unroll
    for (int t = 0; t < T_; ++t) { s1[t] = 0.f; s2[t] = 0.f; }
    float F = 0.f, P = 0.f;
    for (int k = tid; k < HW_; k += 1024) {
        int i = k >> 8, j = k & 255;
        float x = xb[k];
        float p = 1.0f / (1.0f + expf(-x));
        float spn = softplusf(-x);
        float spp = softplusf(x);
        float om = 1.0f - p;
        float fp = 0.25f * om * om * spn;
        float fn = 0.75f * p * p * spp;
        F += fn; P += p;
        float diff = fp - fn;
        int off0 = i * 1024 + 2 * j;
#pragma unroll
        for (int t = 0; t < T_; ++t) {
            float lab = mlb[t * 262144 + off0];
            s1[t] = fmaf(diff, lab, s1[t]);
            s2[t] = fmaf(p,    lab, s2[t]);
        }
    }
    __shared__ float sbuf[16][42];
    int wid = tid >> 6, lane = tid & 63;
#pragma unroll
    for (int t = 0; t < T_; ++t) {
        for (int off = 32; off > 0; off >>= 1) {
            s1[t] += __shfl_down(s1[t], off);
            s2[t] += __shfl_down(s2[t], off);
        }
    }
    for (int off = 32; off > 0; off >>= 1) { F += __shfl_down(F, off); P += __shfl_down(P, off); }
    if (lane == 0) {
#pragma unroll
        for (int t = 0; t < T_; ++t) { sbuf[wid][t] = s1[t]; sbuf[wid][T_ + t] = s2[t]; }
        sbuf[wid][40] = F; sbuf[wid][41] = P;
    }
    __syncthreads();
    if (tid < T_) {
        float S1 = 0.f, S2 = 0.f, Fs = 0.f, Ps = 0.f;
        for (int w = 0; w < 16; ++w) {
            S1 += sbuf[w][tid]; S2 += sbuf[w][T_ + tid];
            Fs += sbuf[w][40];  Ps += sbuf[w][41];
        }
        float L = 0.f;
        for (int sl = 0; sl < 8; ++sl) L += lab_ps[(b * T_ + tid) * 8 + sl];
        float cm = (S1 + Fs) * (1.0f / (float)HW_);
        float cd = 1.0f - (2.0f * S2 + 1.0f) / (Ps + L + 1.0f);
        cost[bq * T_ + tid] = cm + cd + cc[bq * T_ + tid];
    }
}

extern "C" void kernel_launch(void* const* d_in, const int* in_sizes, int n_in,
                              void* d_out, int out_size, void* d_ws, size_t ws_size,
                              hipStream_t stream) {
    const float* mq     = (const float*)d_in[0];   // [2,100,256,256]
    const float* cl     = (const float*)d_in[1];   // [2,100,134]
    const float* ml     = (const float*)d_in[2];   // [2,20,512,512]
    const int*   labels = (const int*)d_in[3];     // [2,20]
    int* out = (int*)d_out;                        // [2,2,20] int32
    float* ws = (float*)d_ws;

    float* lab_ps = ws + LABPS_OFF;
    float* cc     = ws + CC_OFF;
    float* cost   = ws + COST_OFF;

    size_t need = (size_t)WS_END_F * 4;

    if (ws_size >= need) {
        float* part = ws + PART_OFF;
        float* Csum = ws + CSUM_OFF;
        hipLaunchKernelGGL(focal_mfma_kernel,  dim3(B_ * KSB * MT_), dim3(256), 0, stream,
                           mq, ml, part);
        hipLaunchKernelGGL(reduce_part_kernel, dim3(B_ * MT_, 33), dim3(256), 0, stream,
                           part, Csum);
        hipLaunchKernelGGL(hungarian_kernel,   dim3(B_), dim3(256), 0, stream,
                           Csum, cl, labels, cost, out, 1);
    } else {
        hipLaunchKernelGGL(lab_prep_kernel,    dim3(B_, T_, 8), dim3(256), 0, stream,
                           ml, lab_ps);
        hipLaunchKernelGGL(class_cost_kernel,  dim3(B_ * Q_), dim3(64), 0, stream,
                           cl, labels, cc);
        hipLaunchKernelGGL(mask_cost_mono_kernel, dim3(B_ * Q_), dim3(1024), 0, stream,
                           mq, ml, cc, lab_ps, cost);
        hipLaunchKernelGGL(hungarian_kernel,   dim3(B_), dim3(256), 0, stream,
                           ws, cl, labels, cost, out, 0);
    }
}

// Round 17
// 74.234 us; speedup vs baseline: 6.4186x; 1.2827x over previous
//
#include <hip/hip_runtime.h>
#include <hip/hip_bf16.h>
#include <math.h>

#define HW_   65536
#define B_    2
#define Q_    100
#define C_    134
#define T_    20
#define NHUN  100
#define MT_   7            // M-tiles of 16 queries (112 >= 100)
#define KSB   128          // K-split blocks per (b,mt)
#define BKCH  512          // k per block
#define PREC  1088         // part record stride (1024 frag + 16 F + 16 P + pad)
#define CPAD  21           // padded cost row stride (floats) in hungarian LDS

typedef __attribute__((ext_vector_type(8))) short bf16x8;
typedef __attribute__((ext_vector_type(4))) float f32x4;

// ws layout (float units)
#define LABPS_OFF  0                    // [2][20][8]
#define CC_OFF     512                  // [200][20] (fallback path only)
#define COST_OFF   4608                 // [200][20]
#define BASE_END   8704
#define LABT_HI_F  BASE_END                         // 2*20*65536 ushort = 1,310,720 floats
#define PART_OFF   (LABT_HI_F + 1310720)            // 1792 records * 1088 floats
#define CSUM_OFF   (PART_OFF + B_ * KSB * MT_ * PREC)   // 14*1056
#define WS_END_F   (CSUM_OFF + B_ * MT_ * 1056)

__device__ inline unsigned short f2bf(float f) {
    unsigned int u = __builtin_bit_cast(unsigned int, f);
    u += 0x7FFFu + ((u >> 16) & 1u);               // RNE
    return (unsigned short)(u >> 16);
}
__device__ inline float softplusf(float x) {
    float ax = fabsf(x);
    return fmaxf(x, 0.0f) + log1pf(expf(-ax));
}

// ---------------- K1: decimate labels -> bf16 rows [b][t][65536] + row-sum partials (R13) ----------------
__global__ void lab_prep_kernel(const float* __restrict__ ml, unsigned short* __restrict__ labT,
                                float* __restrict__ lab_ps, int writeT) {
    int b = blockIdx.x, t = blockIdx.y, ksl = blockIdx.z;
    int tid = threadIdx.x;
    const float* src = ml + (size_t)(b * T_ + t) * 262144;
    size_t dst = ((size_t)(b * T_ + t)) << 16;
    float acc = 0.f;
    for (int it = 0; it < 8; ++it) {
        int k = ksl * 8192 + it * 1024 + tid * 4;
        int r = k >> 8, c = k & 255;
        const float* s = src + r * 1024 + 2 * c;
        float4 u = *(const float4*)s;
        float4 w = *(const float4*)(s + 4);
        float v[4] = {u.x, u.z, w.x, w.z};
        unsigned short h[4];
#pragma unroll
        for (int e = 0; e < 4; ++e) { h[e] = f2bf(v[e]); acc += v[e]; }
        if (writeT) *(ushort4*)(labT + dst + k) = make_ushort4(h[0], h[1], h[2], h[3]);
    }
    for (int off = 32; off > 0; off >>= 1) acc += __shfl_down(acc, off);
    __shared__ float sb[4];
    int wid = tid >> 6, lane = tid & 63;
    if (lane == 0) sb[wid] = acc;
    __syncthreads();
    if (tid == 0) lab_ps[(b * T_ + t) * 8 + ksl] = sb[0] + sb[1] + sb[2] + sb[3];
}

// ---------------- class cost (fallback path only) ----------------
__global__ void class_cost_kernel(const float* __restrict__ cl, const int* __restrict__ labels,
                                  float* __restrict__ cc) {
    int bq  = blockIdx.x;
    int b   = bq / Q_;
    int tid = threadIdx.x;         // 64
    __shared__ float sl[C_];
    const float* src = cl + (size_t)bq * C_;
    for (int c = tid; c < C_; c += 64) sl[c] = src[c];
    __syncthreads();
    float mx = -INFINITY;
    for (int c = tid; c < C_; c += 64) mx = fmaxf(mx, sl[c]);
    for (int off = 32; off > 0; off >>= 1) mx = fmaxf(mx, __shfl_xor(mx, off));
    float se = 0.f;
    for (int c = tid; c < C_; c += 64) se += expf(sl[c] - mx);
    for (int off = 32; off > 0; off >>= 1) se += __shfl_xor(se, off);
    float inv = 1.0f / se;
    if (tid < T_) {
        int lbl = labels[b * T_ + tid];
        cc[bq * T_ + tid] = -expf(sl[lbl] - mx) * inv;
    }
}

// ---------------- K3: LDS-staged focal MFMA (coalesced global, swizzled LDS fragments) ----------------
// blockIdx.x = (b*KSB + ks)*MT_ + mt ; 256 thr (4 waves).
// Phase 1: coalesced row loads (mq 2KB/row, labT 1KB/row) -> pointwise -> swizzled LDS tiles.
// Phase 2: ds_read_b128 fragments (XOR swizzle blk^=(row&7), same formula both sides) + MFMA.
// LDS: dh [0,16K), ph [16K,32K), B [32K,52K); red reuses [0,16K) after barrier.
__global__ __launch_bounds__(256, 3) void focal_mfma_kernel(
        const float* __restrict__ mq, const unsigned short* __restrict__ labT,
        float* __restrict__ part) {
    int idx = blockIdx.x;
    int mt  = idx % MT_;
    int rem = idx / MT_;
    int ks  = rem % KSB;
    int b   = rem / KSB;
    int tid  = threadIdx.x;
    int wave = tid >> 6, lane = tid & 63;
    int lg = lane >> 4, lr = lane & 15;

    __shared__ __align__(16) char smem[53504];

    // ---- phase 1a: B staging (wave w stages labT rows w+4i, i=0..4; 1KB contiguous each) ----
    for (int i = 0; i < 5; ++i) {
        int t  = wave + 4 * i;                    // 0..19
        int k0 = lane * 8;
        bf16x8 v = *(const bf16x8*)(labT + (((size_t)(b * T_ + t)) << 16) + ks * BKCH + k0);
        int byte = 32768 + t * 1024 + (((k0 >> 3) ^ (t & 7)) << 4);
        *(bf16x8*)(smem + byte) = v;
    }

    // ---- phase 1b: A rows (wave w owns tile rows 4w..4w+3; 2x1KB coalesced loads per row) ----
    float Fr[4], Pr[4];
#pragma unroll
    for (int rr = 0; rr < 4; ++rr) { Fr[rr] = 0.f; Pr[rr] = 0.f; }
#pragma unroll
    for (int i = 0; i < 8; ++i) {
        int rr   = i >> 1;
        int r    = wave * 4 + rr;                 // tile row 0..15
        int half = i & 1;
        int k0   = half * 256 + lane * 4;         // k in [0,512)
        int q    = mt * 16 + r;
        bool qok = (q < Q_);
        const float* xr = mq + ((size_t)(b * Q_ + (qok ? q : 0)) << 16) + ks * BKCH;
        float4 xv = *(const float4*)(xr + k0);
        unsigned short dh[4], ph[4];
        float Fs = 0.f, Ps = 0.f;
#pragma unroll
        for (int e = 0; e < 4; ++e) {
            float x  = (&xv.x)[e];
            float ax = fabsf(x);
            float a  = __expf(-ax);
            float rcp = 1.0f / (1.0f + a);
            float p  = (x >= 0.f) ? rcp : a * rcp;
            float om = (x >= 0.f) ? a * rcp : rcp;
            float l1 = __logf(1.0f + a);
            float spn = fmaxf(-x, 0.f) + l1;      // softplus(-x)
            float spp = spn + x;                  // softplus(x)
            float fp = 0.25f * om * om * spn;
            float fn = 0.75f * p * p * spp;
            Fs += fn; Ps += p;
            dh[e] = f2bf(fp - fn);
            ph[e] = f2bf(p);
        }
        Fr[rr] += Fs; Pr[rr] += Ps;
        if ((mt == 6) && (r == 4)) {              // ones-row (lab row sums via MFMA)
            dh[0] = dh[1] = dh[2] = dh[3] = 0x3F80;
            ph[0] = ph[1] = ph[2] = ph[3] = 0x3F80;
        }
        uint2 dv, pv;
        dv.x = (unsigned)dh[0] | ((unsigned)dh[1] << 16);
        dv.y = (unsigned)dh[2] | ((unsigned)dh[3] << 16);
        pv.x = (unsigned)ph[0] | ((unsigned)ph[1] << 16);
        pv.y = (unsigned)ph[2] | ((unsigned)ph[3] << 16);
        int byte = r * 1024 + (((k0 >> 3) ^ (r & 7)) << 4) + ((k0 & 7) * 2);
        *(uint2*)(smem + byte)         = dv;
        *(uint2*)(smem + 16384 + byte) = pv;
    }
    __syncthreads();

    // ---- phase 2: swizzled ds_read_b128 fragments + MFMA ----
    f32x4 accD0 = {0,0,0,0}, accD1 = {0,0,0,0};
    f32x4 accP0 = {0,0,0,0}, accP1 = {0,0,0,0};
    bf16x8 zer;
#pragma unroll
    for (int e = 0; e < 8; ++e) zer[e] = 0;
#pragma unroll
    for (int kk = 0; kk < 4; ++kk) {
        int k  = wave * 128 + kk * 32 + lg * 8;
        int ab = lr * 1024 + (((k >> 3) ^ (lr & 7)) << 4);
        bf16x8 dh = *(const bf16x8*)(smem + ab);
        bf16x8 ph = *(const bf16x8*)(smem + 16384 + ab);
        int t1 = lr;
        bf16x8 f1 = *(const bf16x8*)(smem + 32768 + t1 * 1024 + (((k >> 3) ^ (t1 & 7)) << 4));
        bf16x8 f2 = zer;
        if (lr < 4) {
            int t2 = 16 + lr;
            f2 = *(const bf16x8*)(smem + 32768 + t2 * 1024 + (((k >> 3) ^ (t2 & 7)) << 4));
        }
        accD0 = __builtin_amdgcn_mfma_f32_16x16x32_bf16(dh, f1, accD0, 0, 0, 0);
        accD1 = __builtin_amdgcn_mfma_f32_16x16x32_bf16(dh, f2, accD1, 0, 0, 0);
        accP0 = __builtin_amdgcn_mfma_f32_16x16x32_bf16(ph, f1, accP0, 0, 0, 0);
        accP1 = __builtin_amdgcn_mfma_f32_16x16x32_bf16(ph, f2, accP1, 0, 0, 0);
    }
    __syncthreads();     // tiles dead; reuse smem

    // ---- reduction & store ----
    float (*red)[4][64][4] = (float (*)[4][64][4])smem;          // 16 KB @0
    float* fpF = (float*)(smem + 16384);                          // [16]
    float* fpP = (float*)(smem + 16384 + 64);                     // [16]
#pragma unroll
    for (int r = 0; r < 4; ++r) {
        red[wave][0][lane][r] = accD0[r];
        red[wave][1][lane][r] = accD1[r];
        red[wave][2][lane][r] = accP0[r];
        red[wave][3][lane][r] = accP1[r];
    }
#pragma unroll
    for (int rr = 0; rr < 4; ++rr) {
        float f = Fr[rr], p = Pr[rr];
        for (int off = 32; off > 0; off >>= 1) {
            f += __shfl_down(f, off);
            p += __shfl_down(p, off);
        }
        if (lane == 0) { fpF[wave * 4 + rr] = f; fpP[wave * 4 + rr] = p; }
    }
    __syncthreads();
    {
        int e4 = tid;                      // 256 float4 groups = 1024 floats
        int f  = e4 >> 6;
        int l2 = e4 & 63;
        float4 s;
        s.x = red[0][f][l2][0] + red[1][f][l2][0] + red[2][f][l2][0] + red[3][f][l2][0];
        s.y = red[0][f][l2][1] + red[1][f][l2][1] + red[2][f][l2][1] + red[3][f][l2][1];
        s.z = red[0][f][l2][2] + red[1][f][l2][2] + red[2][f][l2][2] + red[3][f][l2][2];
        s.w = red[0][f][l2][3] + red[1][f][l2][3] + red[2][f][l2][3] + red[3][f][l2][3];
        *(float4*)(part + (size_t)idx * PREC + e4 * 4) = s;
    }
    if (tid < 16)
        part[(size_t)idx * PREC + 1024 + tid] = fpF[tid];
    else if (tid < 32)
        part[(size_t)idx * PREC + 1040 + (tid - 16)] = fpP[tid - 16];
}

// ---------------- K4a: parallel K-split reduction: part -> Csum[14][1056] (R13) ----------------
__global__ __launch_bounds__(256) void reduce_part_kernel(const float* __restrict__ part,
                                                          float* __restrict__ Csum) {
    int bm   = blockIdx.x;          // 0..13
    int mt   = bm % MT_;
    int b    = bm / MT_;
    int tid  = threadIdx.x;
    int epos = tid & 31;
    int grp  = tid >> 5;            // 0..7
    int e    = blockIdx.y * 32 + epos;   // 0..1055

    const float* base = part + (size_t)((b * KSB) * MT_ + mt) * PREC + e;
    float s = 0.f;
    for (int k = 0; k < 16; ++k)
        s += base[(size_t)(grp * 16 + k) * MT_ * PREC];
    __shared__ float red[8][33];
    red[grp][epos] = s;
    __syncthreads();
    if (tid < 32) {
        float tot = 0.f;
        for (int g = 0; g < 8; ++g) tot += red[g][tid];
        Csum[(size_t)bm * 1056 + e] = tot;
    }
}

// ---------------- K4b: finalize cost from Csum + fused class-softmax (R13-proven) ----------------
__global__ __launch_bounds__(320) void compose_kernel(
        const float* __restrict__ Csum, const float* __restrict__ cl,
        const int* __restrict__ labels, const float* __restrict__ lab_ps,
        float* __restrict__ cost) {
    int bm = blockIdx.x;
    int mt = bm % MT_;
    int b  = bm / MT_;
    int tid = threadIdx.x;     // 320
    int q0 = mt * 16;

    __shared__ float sl[16][136];
    __shared__ float mx[16], se[16];
    __shared__ int   lbl[T_];
    for (int e = tid; e < 16 * C_; e += 320) {
        int qm = e / C_, c = e % C_;
        int q = q0 + qm;
        sl[qm][c] = (q < Q_) ? cl[(size_t)(b * Q_ + q) * C_ + c] : 0.f;
    }
    if (tid < T_) lbl[tid] = labels[b * T_ + tid];
    __syncthreads();
    if (tid < 16) {
        float m = -INFINITY;
        for (int c = 0; c < C_; ++c) m = fmaxf(m, sl[tid][c]);
        float s = 0.f;
        for (int c = 0; c < C_; ++c) s += expf(sl[tid][c] - m);
        mx[tid] = m; se[tid] = s;
    }
    __syncthreads();

    int qm = tid / T_, t = tid % T_;
    int q = q0 + qm;
    if (qm < 16 && q < Q_) {
        const float* C = Csum + (size_t)bm * 1056;
        int nt   = t >> 4;
        int lane = ((qm >> 2) << 4) | (t & 15);
        int reg  = qm & 3;
        float Sd = C[(0 + nt) * 256 + lane * 4 + reg];
        float Sp = C[(2 + nt) * 256 + lane * 4 + reg];
        float F  = C[1024 + qm];
        float P  = C[1040 + qm];
        float L = 0.f;
        for (int s8 = 0; s8 < 8; ++s8) L += lab_ps[(b * T_ + t) * 8 + s8];
        float ccv = -expf(sl[qm][lbl[t]] - mx[qm]) / se[qm];
        float cm = (Sd + F) * (1.0f / (float)HW_);
        float cd = 1.0f - (2.0f * Sp + 1.0f) / (P + L + 1.0f);
        cost[(size_t)(b * Q_ + q) * T_ + t] = cm + cd + ccv;
    }
}

// ---------------- fallback: monolithic (round-2 proven) ----------------
__global__ __launch_bounds__(1024) void mask_cost_mono_kernel(
        const float* __restrict__ mq, const float* __restrict__ ml,
        const float* __restrict__ cc, const float* __restrict__ lab_ps,
        float* __restrict__ cost) {
    int bq  = blockIdx.x;
    int b   = bq / Q_;
    int tid = threadIdx.x;
    const float* xb  = mq + (size_t)bq * HW_;
    const float* mlb = ml + (size_t)b * T_ * 262144;
    float s1[T_], s2[T_];
#pragma unroll
    for (int t = 0; t < T_; ++t) { s1[t] = 0.f; s2[t] = 0.f; }
    float F = 0.f, P = 0.f;
    for (int k = tid; k < HW_; k += 1024) {
        int i = k >> 8, j = k & 255;
        float x = xb[k];
        float p = 1.0f / (1.0f + expf(-x));
        float spn = softplusf(-x);
        float spp = softplusf(x);
        float om = 1.0f - p;
        float fp = 0.25f * om * om * spn;
        float fn = 0.75f * p * p * spp;
        F += fn; P += p;
        float diff = fp - fn;
        int off0 = i * 1024 + 2 * j;
#pragma unroll
        for (int t = 0; t < T_; ++t) {
            float lab = mlb[t * 262144 + off0];
            s1[t] = fmaf(diff, lab, s1[t]);
            s2[t] = fmaf(p,    lab, s2[t]);
        }
    }
    __shared__ float sbuf[16][42];
    int wid = tid >> 6, lane = tid & 63;
#pragma unroll
    for (int t = 0; t < T_; ++t) {
        for (int off = 32; off > 0; off >>= 1) {
            s1[t] += __shfl_down(s1[t], off);
            s2[t] += __shfl_down(s2[t], off);
        }
    }
    for (int off = 32; off > 0; off >>= 1) { F += __shfl_down(F, off); P += __shfl_down(P, off); }
    if (lane == 0) {
#pragma unroll
        for (int t = 0; t < T_; ++t) { sbuf[wid][t] = s1[t]; sbuf[wid][T_ + t] = s2[t]; }
        sbuf[wid][40] = F; sbuf[wid][41] = P;
    }
    __syncthreads();
    if (tid < T_) {
        float S1 = 0.f, S2 = 0.f, Fs = 0.f, Ps = 0.f;
        for (int w = 0; w < 16; ++w) {
            S1 += sbuf[w][tid]; S2 += sbuf[w][T_ + tid];
            Fs += sbuf[w][40];  Ps += sbuf[w][41];
        }
        float L = 0.f;
        for (int sl = 0; sl < 8; ++sl) L += lab_ps[(b * T_ + tid) * 8 + sl];
        float cm = (S1 + Fs) * (1.0f / (float)HW_);
        float cd = 1.0f - (2.0f * S2 + 1.0f) / (Ps + L + 1.0f);
        cost[bq * T_ + tid] = cm + cd + cc[bq * T_ + tid];
    }
}

// ---------------- K5: register-resident JV Hungarian with greedy init (R12/R13-proven) ----------------
__global__ __launch_bounds__(64) void hungarian_kernel(const float* __restrict__ cost,
                                                       int* __restrict__ out) {
    int b    = blockIdx.x;
    int lane = threadIdx.x;

    __shared__ float csh[Q_ * CPAD];
    __shared__ int   psh[NHUN + 1];

    for (int j = lane; j < Q_; j += 64) {
#pragma unroll
        for (int t = 0; t < T_; ++t)
            csh[j * CPAD + t] = cost[b * Q_ * T_ + j * T_ + t];
    }
    __syncthreads();

    const int ja = lane;
    const int jb = lane + 64;
    const bool ja_ok = (ja >= 1);
    const bool jb_ok = (jb <= NHUN);

    int   p_a = 0, p_b = 0;
    float v_a = 0.f, v_b = 0.f;
    float u_reg = 0.f;

    for (int i = 1; i <= T_; ++i) {
        float ca = ja_ok ? csh[(ja - 1) * CPAD + (i - 1)] : INFINITY;
        float cb = jb_ok ? csh[(jb - 1) * CPAD + (i - 1)] : INFINITY;
        float vmin = fminf(ca, cb);
        for (int off = 32; off > 0; off >>= 1)
            vmin = fminf(vmin, __shfl_xor(vmin, off));
        unsigned long long ba = __ballot(ca == vmin);
        int j1 = ba ? (__ffsll(ba) - 1) : (__ffsll(__ballot(cb == vmin)) - 1 + 64);
        if (lane == i) u_reg = vmin;
        int pj = __shfl((j1 < 64) ? p_a : p_b, j1 & 63);
        if (pj == 0) {
            if (j1 < 64) { if (lane == j1) p_a = i; }
            else         { if (lane == j1 - 64) p_b = i; }
        }
    }

    for (int i = 1; i <= T_; ++i) {
        bool mine = (p_a == i) || (p_b == i);
        if (__ballot(mine)) continue;

        float m_a = INFINITY, m_b = INFINITY;
        int   way_a = 0, way_b = 0;
        bool  us_a = false, us_b = false;
        bool  in_tree = (lane == i);
        int   j0 = 0, jf;

        while (true) {
            int i0 = (j0 == 0) ? i : __shfl((j0 < 64) ? p_a : p_b, j0 & 63);
            if (lane == i0) in_tree = true;
            float ui0 = __shfl(u_reg, i0);
            if (ja == j0) us_a = true;
            if (jb == j0) us_b = true;
            bool fa = ja_ok && !us_a;
            bool fb = jb_ok && !us_b;
            if (fa) {
                float cur = csh[(ja - 1) * CPAD + (i0 - 1)] - ui0 - v_a;
                if (cur < m_a) { m_a = cur; way_a = j0; }
            }
            if (fb) {
                float cur = csh[(jb - 1) * CPAD + (i0 - 1)] - ui0 - v_b;
                if (cur < m_b) { m_b = cur; way_b = j0; }
            }
            float ca = fa ? m_a : INFINITY;
            float cb = fb ? m_b : INFINITY;
            float vmin = fminf(ca, cb);
            for (int off = 32; off > 0; off >>= 1)
                vmin = fminf(vmin, __shfl_xor(vmin, off));
            unsigned long long ba = __ballot(ca == vmin);
            int j1 = ba ? (__ffsll(ba) - 1) : (__ffsll(__ballot(cb == vmin)) - 1 + 64);
            float delta = vmin;
            if (us_a) v_a -= delta; else m_a -= delta;
            if (us_b) v_b -= delta; else m_b -= delta;
            if (in_tree) u_reg += delta;
            j0 = j1;
            int pj0 = __shfl((j0 < 64) ? p_a : p_b, j0 & 63);
            if (pj0 == 0) { jf = j0; break; }
        }
        int jj = jf;
        while (jj) {
            int wv = __shfl((jj < 64) ? way_a : way_b, jj & 63);
            int pn = (wv == 0) ? i : __shfl((wv < 64) ? p_a : p_b, wv & 63);
            if (jj < 64) { if (lane == jj) p_a = pn; }
            else         { if (lane == jj - 64) p_b = pn; }
            jj = wv;
        }
    }

    if (ja_ok) psh[ja] = p_a;
    if (jb_ok) psh[jb] = p_b;
    if (lane == 0) psh[0] = 0;
    __syncthreads();
    if (lane == 0) {
        int* ob = out + b * 2 * T_;
        int k = 0;
        for (int j = 1; j <= NHUN; ++j) {
            if (psh[j] != 0) { ob[k] = j - 1; ob[T_ + k] = psh[j] - 1; ++k; }
        }
    }
}

extern "C" void kernel_launch(void* const* d_in, const int* in_sizes, int n_in,
                              void* d_out, int out_size, void* d_ws, size_t ws_size,
                              hipStream_t stream) {
    const float* mq     = (const float*)d_in[0];   // [2,100,256,256]
    const float* cl     = (const float*)d_in[1];   // [2,100,134]
    const float* ml     = (const float*)d_in[2];   // [2,20,512,512]
    const int*   labels = (const int*)d_in[3];     // [2,20]
    int* out = (int*)d_out;                        // [2,2,20] int32
    float* ws = (float*)d_ws;

    float* lab_ps = ws + LABPS_OFF;
    float* cc     = ws + CC_OFF;
    float* cost   = ws + COST_OFF;

    size_t need = (size_t)WS_END_F * 4;

    if (ws_size >= need) {
        unsigned short* labT = (unsigned short*)(ws + LABT_HI_F);
        float* part = ws + PART_OFF;
        float* Csum = ws + CSUM_OFF;
        hipLaunchKernelGGL(lab_prep_kernel,   dim3(B_, T_, 8), dim3(256), 0, stream,
                           ml, labT, lab_ps, 1);
        hipLaunchKernelGGL(focal_mfma_kernel, dim3(B_ * KSB * MT_), dim3(256), 0, stream,
                           mq, labT, part);
        hipLaunchKernelGGL(reduce_part_kernel, dim3(B_ * MT_, 33), dim3(256), 0, stream,
                           part, Csum);
        hipLaunchKernelGGL(compose_kernel,    dim3(B_ * MT_),  dim3(320), 0, stream,
                           Csum, cl, labels, lab_ps, cost);
    } else {
        hipLaunchKernelGGL(lab_prep_kernel,   dim3(B_, T_, 8), dim3(256), 0, stream,
                           ml, (unsigned short*)ws, lab_ps, 0);
        hipLaunchKernelGGL(class_cost_kernel, dim3(B_ * Q_),   dim3(64),  0, stream, cl, labels, cc);
        hipLaunchKernelGGL(mask_cost_mono_kernel, dim3(B_ * Q_), dim3(1024), 0, stream,
                           mq, ml, cc, lab_ps, cost);
    }
    hipLaunchKernelGGL(hungarian_kernel, dim3(B_), dim3(64), 0, stream, cost, out);
}

// Round 18
// 69.902 us; speedup vs baseline: 6.8164x; 1.0620x over previous
//
#include <hip/hip_runtime.h>
#include <hip/hip_bf16.h>
#include <math.h>

#define HW_   65536
#define B_    2
#define Q_    100
#define C_    134
#define T_    20
#define NHUN  100
#define MT_   7            // M-tiles of 16 queries (112 >= 100)
#define KSB   128          // K-split blocks per (b,mt)
#define BKCH  512          // k per block
#define PREC  1088         // part record stride (1024 frag + 16 F + 16 P + pad)
#define CPAD  21           // padded cost row stride (floats) in hungarian LDS

typedef __attribute__((ext_vector_type(8))) short bf16x8;
typedef __attribute__((ext_vector_type(4))) float f32x4;

// ws layout (float units)
#define LABPS_OFF  0                    // [2][20][8]
#define CC_OFF     512                  // [200][20] (fallback path only)
#define COST_OFF   4608                 // [200][20]
#define BASE_END   8704
#define LABT_HI_F  BASE_END                         // 2*20*65536 ushort = 1,310,720 floats
#define PART_OFF   (LABT_HI_F + 1310720)            // 1792 records * 1088 floats
#define CSUM_OFF   (PART_OFF + B_ * KSB * MT_ * PREC)   // 14*1056
#define WS_END_F   (CSUM_OFF + B_ * MT_ * 1056)

__device__ inline unsigned short f2bf(float f) {
    unsigned int u = __builtin_bit_cast(unsigned int, f);
    u += 0x7FFFu + ((u >> 16) & 1u);               // RNE
    return (unsigned short)(u >> 16);
}
__device__ inline float softplusf(float x) {
    float ax = fabsf(x);
    return fmaxf(x, 0.0f) + log1pf(expf(-ax));
}

// ---------------- K1: decimate labels -> bf16 rows [b][t][65536] + row-sum partials ----------------
__global__ void lab_prep_kernel(const float* __restrict__ ml, unsigned short* __restrict__ labT,
                                float* __restrict__ lab_ps, int writeT) {
    int b = blockIdx.x, t = blockIdx.y, ksl = blockIdx.z;
    int tid = threadIdx.x;
    const float* src = ml + (size_t)(b * T_ + t) * 262144;
    size_t dst = ((size_t)(b * T_ + t)) << 16;
    float acc = 0.f;
    for (int it = 0; it < 8; ++it) {
        int k = ksl * 8192 + it * 1024 + tid * 4;
        int r = k >> 8, c = k & 255;
        const float* s = src + r * 1024 + 2 * c;
        float4 u = *(const float4*)s;
        float4 w = *(const float4*)(s + 4);
        float v[4] = {u.x, u.z, w.x, w.z};
        unsigned short h[4];
#pragma unroll
        for (int e = 0; e < 4; ++e) { h[e] = f2bf(v[e]); acc += v[e]; }
        if (writeT) *(ushort4*)(labT + dst + k) = make_ushort4(h[0], h[1], h[2], h[3]);
    }
    for (int off = 32; off > 0; off >>= 1) acc += __shfl_down(acc, off);
    __shared__ float sb[4];
    int wid = tid >> 6, lane = tid & 63;
    if (lane == 0) sb[wid] = acc;
    __syncthreads();
    if (tid == 0) lab_ps[(b * T_ + t) * 8 + ksl] = sb[0] + sb[1] + sb[2] + sb[3];
}

// ---------------- class cost (fallback path only) ----------------
__global__ void class_cost_kernel(const float* __restrict__ cl, const int* __restrict__ labels,
                                  float* __restrict__ cc) {
    int bq  = blockIdx.x;
    int b   = bq / Q_;
    int tid = threadIdx.x;         // 64
    __shared__ float sl[C_];
    const float* src = cl + (size_t)bq * C_;
    for (int c = tid; c < C_; c += 64) sl[c] = src[c];
    __syncthreads();
    float mx = -INFINITY;
    for (int c = tid; c < C_; c += 64) mx = fmaxf(mx, sl[c]);
    for (int off = 32; off > 0; off >>= 1) mx = fmaxf(mx, __shfl_xor(mx, off));
    float se = 0.f;
    for (int c = tid; c < C_; c += 64) se += expf(sl[c] - mx);
    for (int off = 32; off > 0; off >>= 1) se += __shfl_xor(se, off);
    float inv = 1.0f / se;
    if (tid < T_) {
        int lbl = labels[b * T_ + tid];
        cc[bq * T_ + tid] = -expf(sl[lbl] - mx) * inv;
    }
}

// ---------------- K3: focal MFMA with full-block prefetch (R13-proven best) ----------------
__global__ __launch_bounds__(256, 4) void focal_mfma_kernel(
        const float* __restrict__ mq, const unsigned short* __restrict__ labT,
        float* __restrict__ part) {
    int idx = blockIdx.x;
    int mt  = idx % MT_;
    int rem = idx / MT_;
    int ks  = rem % KSB;
    int b   = rem / KSB;
    int tid  = threadIdx.x;
    int wave = tid >> 6, lane = tid & 63;
    int lg = lane >> 4, lr = lane & 15;

    int q = mt * 16 + lr;
    bool qok = (q < Q_);
    const float* xrow = mq + ((size_t)(b * Q_ + (qok ? q : 0)) << 16);
    int koff = ks * BKCH + wave * 128 + lg * 8;

    const unsigned short* b1 = labT + (((size_t)(b * T_ + lr)) << 16);
    const unsigned short* b2 = labT + (((size_t)(b * T_ + 16 + (lr & 3))) << 16);
    bool n2row = (lr < 4);

    bf16x8 zer;
#pragma unroll
    for (int e = 0; e < 8; ++e) zer[e] = 0;

    // ---- prefetch: 16 independent loads in flight ----
    float4 a0[4], a1[4];
    bf16x8 bfrag1[4], bfrag2[4];
#pragma unroll
    for (int kk = 0; kk < 4; ++kk) {
        int kb = koff + kk * 32;
        a0[kk] = *(const float4*)(xrow + kb);
        a1[kk] = *(const float4*)(xrow + kb + 4);
        bfrag1[kk] = *(const bf16x8*)(b1 + kb);
        bfrag2[kk] = n2row ? *(const bf16x8*)(b2 + kb) : zer;
    }

    f32x4 accD0 = {0,0,0,0}, accD1 = {0,0,0,0};
    f32x4 accP0 = {0,0,0,0}, accP1 = {0,0,0,0};
    float F = 0.f, P = 0.f;

#pragma unroll
    for (int kk = 0; kk < 4; ++kk) {
        float xv[8] = {a0[kk].x, a0[kk].y, a0[kk].z, a0[kk].w,
                       a1[kk].x, a1[kk].y, a1[kk].z, a1[kk].w};
        bf16x8 dh, ph;
#pragma unroll
        for (int e = 0; e < 8; ++e) {
            float x  = xv[e];
            float ax = fabsf(x);
            float a  = __expf(-ax);
            float rr = 1.0f / (1.0f + a);
            float p  = (x >= 0.f) ? rr : a * rr;
            float om = (x >= 0.f) ? a * rr : rr;
            float l1 = __logf(1.0f + a);
            float spn = fmaxf(-x, 0.f) + l1;
            float spp = spn + x;
            float fp = 0.25f * om * om * spn;
            float fn = 0.75f * p * p * spp;
            F += fn; P += p;
            dh[e] = (short)f2bf(fp - fn);
            ph[e] = (short)f2bf(p);
        }
        accD0 = __builtin_amdgcn_mfma_f32_16x16x32_bf16(dh, bfrag1[kk], accD0, 0, 0, 0);
        accD1 = __builtin_amdgcn_mfma_f32_16x16x32_bf16(dh, bfrag2[kk], accD1, 0, 0, 0);
        accP0 = __builtin_amdgcn_mfma_f32_16x16x32_bf16(ph, bfrag1[kk], accP0, 0, 0, 0);
        accP1 = __builtin_amdgcn_mfma_f32_16x16x32_bf16(ph, bfrag2[kk], accP1, 0, 0, 0);
    }

    F += __shfl_down(F, 32); F += __shfl_down(F, 16);
    P += __shfl_down(P, 32); P += __shfl_down(P, 16);

    __shared__ float red[4][4][64][4];
    __shared__ float fpb[4][2][16];
#pragma unroll
    for (int r = 0; r < 4; ++r) {
        red[wave][0][lane][r] = accD0[r];
        red[wave][1][lane][r] = accD1[r];
        red[wave][2][lane][r] = accP0[r];
        red[wave][3][lane][r] = accP1[r];
    }
    if (lane < 16) { fpb[wave][0][lane] = F; fpb[wave][1][lane] = P; }
    __syncthreads();
    {
        int e4 = tid;                      // 256 float4 groups = 1024 floats
        int f  = e4 >> 6;                  // frag id 0..3
        int l2 = e4 & 63;                  // lane idx
        float4 s;
        s.x = red[0][f][l2][0] + red[1][f][l2][0] + red[2][f][l2][0] + red[3][f][l2][0];
        s.y = red[0][f][l2][1] + red[1][f][l2][1] + red[2][f][l2][1] + red[3][f][l2][1];
        s.z = red[0][f][l2][2] + red[1][f][l2][2] + red[2][f][l2][2] + red[3][f][l2][2];
        s.w = red[0][f][l2][3] + red[1][f][l2][3] + red[2][f][l2][3] + red[3][f][l2][3];
        *(float4*)(part + (size_t)idx * PREC + e4 * 4) = s;
    }
    if (tid < 16)
        part[(size_t)idx * PREC + 1024 + tid] =
            fpb[0][0][tid] + fpb[1][0][tid] + fpb[2][0][tid] + fpb[3][0][tid];
    else if (tid < 32) {
        int l = tid - 16;
        part[(size_t)idx * PREC + 1040 + l] =
            fpb[0][1][l] + fpb[1][1][l] + fpb[2][1][l] + fpb[3][1][l];
    }
}

// ---------------- K4a: parallel K-split reduction: part -> Csum[14][1056] ----------------
__global__ __launch_bounds__(256) void reduce_part_kernel(const float* __restrict__ part,
                                                          float* __restrict__ Csum) {
    int bm   = blockIdx.x;          // 0..13
    int mt   = bm % MT_;
    int b    = bm / MT_;
    int tid  = threadIdx.x;
    int epos = tid & 31;
    int grp  = tid >> 5;            // 0..7
    int e    = blockIdx.y * 32 + epos;   // 0..1055

    const float* base = part + (size_t)((b * KSB) * MT_ + mt) * PREC + e;
    float s = 0.f;
    for (int k = 0; k < 16; ++k) {
        s += base[(size_t)(grp * 16 + k) * MT_ * PREC];
    }
    __shared__ float red[8][33];
    red[grp][epos] = s;
    __syncthreads();
    if (tid < 32) {
        float tot = 0.f;
        for (int g = 0; g < 8; ++g) tot += red[g][tid];
        Csum[(size_t)bm * 1056 + e] = tot;
    }
}

// ---------------- K4b: finalize cost from Csum + fused class-softmax (R8-proven) ----------------
__global__ __launch_bounds__(320) void compose_kernel(
        const float* __restrict__ Csum, const float* __restrict__ cl,
        const int* __restrict__ labels, const float* __restrict__ lab_ps,
        float* __restrict__ cost) {
    int bm = blockIdx.x;
    int mt = bm % MT_;
    int b  = bm / MT_;
    int tid = threadIdx.x;     // 320
    int q0 = mt * 16;

    __shared__ float sl[16][136];
    __shared__ float mx[16], se[16];
    __shared__ int   lbl[T_];
    for (int e = tid; e < 16 * C_; e += 320) {
        int qm = e / C_, c = e % C_;
        int q = q0 + qm;
        sl[qm][c] = (q < Q_) ? cl[(size_t)(b * Q_ + q) * C_ + c] : 0.f;
    }
    if (tid < T_) lbl[tid] = labels[b * T_ + tid];
    __syncthreads();
    if (tid < 16) {
        float m = -INFINITY;
        for (int c = 0; c < C_; ++c) m = fmaxf(m, sl[tid][c]);
        float s = 0.f;
        for (int c = 0; c < C_; ++c) s += expf(sl[tid][c] - m);
        mx[tid] = m; se[tid] = s;
    }
    __syncthreads();

    int qm = tid / T_, t = tid % T_;
    int q = q0 + qm;
    if (qm < 16 && q < Q_) {
        const float* C = Csum + (size_t)bm * 1056;
        int nt   = t >> 4;
        int lane = ((qm >> 2) << 4) | (t & 15);
        int reg  = qm & 3;
        float Sd = C[(0 + nt) * 256 + lane * 4 + reg];
        float Sp = C[(2 + nt) * 256 + lane * 4 + reg];
        float F  = C[1024 + qm];
        float P  = C[1040 + qm];
        float L = 0.f;
        for (int s8 = 0; s8 < 8; ++s8) L += lab_ps[(b * T_ + t) * 8 + s8];
        float ccv = -expf(sl[qm][lbl[t]] - mx[qm]) / se[qm];
        float cm = (Sd + F) * (1.0f / (float)HW_);
        float cd = 1.0f - (2.0f * Sp + 1.0f) / (P + L + 1.0f);
        cost[(size_t)(b * Q_ + q) * T_ + t] = cm + cd + ccv;
    }
}

// ---------------- fallback: monolithic (round-2 proven) ----------------
__global__ __launch_bounds__(1024) void mask_cost_mono_kernel(
        const float* __restrict__ mq, const float* __restrict__ ml,
        const float* __restrict__ cc, const float* __restrict__ lab_ps,
        float* __restrict__ cost) {
    int bq  = blockIdx.x;
    int b   = bq / Q_;
    int tid = threadIdx.x;
    const float* xb  = mq + (size_t)bq * HW_;
    const float* mlb = ml + (size_t)b * T_ * 262144;
    float s1[T_], s2[T_];
#pragma unroll
    for (int t = 0; t < T_; ++t) { s1[t] = 0.f; s2[t] = 0.f; }
    float F = 0.f, P = 0.f;
    for (int k = tid; k < HW_; k += 1024) {
        int i = k >> 8, j = k & 255;
        float x = xb[k];
        float p = 1.0f / (1.0f + expf(-x));
        float spn = softplusf(-x);
        float spp = softplusf(x);
        float om = 1.0f - p;
        float fp = 0.25f * om * om * spn;
        float fn = 0.75f * p * p * spp;
        F += fn; P += p;
        float diff = fp - fn;
        int off0 = i * 1024 + 2 * j;
#pragma unroll
        for (int t = 0; t < T_; ++t) {
            float lab = mlb[t * 262144 + off0];
            s1[t] = fmaf(diff, lab, s1[t]);
            s2[t] = fmaf(p,    lab, s2[t]);
        }
    }
    __shared__ float sbuf[16][42];
    int wid = tid >> 6, lane = tid & 63;
#pragma unroll
    for (int t = 0; t < T_; ++t) {
        for (int off = 32; off > 0; off >>= 1) {
            s1[t] += __shfl_down(s1[t], off);
            s2[t] += __shfl_down(s2[t], off);
        }
    }
    for (int off = 32; off > 0; off >>= 1) { F += __shfl_down(F, off); P += __shfl_down(P, off); }
    if (lane == 0) {
#pragma unroll
        for (int t = 0; t < T_; ++t) { sbuf[wid][t] = s1[t]; sbuf[wid][T_ + t] = s2[t]; }
        sbuf[wid][40] = F; sbuf[wid][41] = P;
    }
    __syncthreads();
    if (tid < T_) {
        float S1 = 0.f, S2 = 0.f, Fs = 0.f, Ps = 0.f;
        for (int w = 0; w < 16; ++w) {
            S1 += sbuf[w][tid]; S2 += sbuf[w][T_ + tid];
            Fs += sbuf[w][40];  Ps += sbuf[w][41];
        }
        float L = 0.f;
        for (int sl = 0; sl < 8; ++sl) L += lab_ps[(b * T_ + tid) * 8 + sl];
        float cm = (S1 + Fs) * (1.0f / (float)HW_);
        float cd = 1.0f - (2.0f * S2 + 1.0f) / (Ps + L + 1.0f);
        cost[bq * T_ + tid] = cm + cd + cc[bq * T_ + tid];
    }
}

// ---------------- K5: register-resident JV Hungarian with greedy row-reduction init (R12-proven) ----------------
__global__ __launch_bounds__(64) void hungarian_kernel(const float* __restrict__ cost,
                                                       int* __restrict__ out) {
    int b    = blockIdx.x;
    int lane = threadIdx.x;

    __shared__ float csh[Q_ * CPAD];
    __shared__ int   psh[NHUN + 1];

    for (int j = lane; j < Q_; j += 64) {
#pragma unroll
        for (int t = 0; t < T_; ++t)
            csh[j * CPAD + t] = cost[b * Q_ * T_ + j * T_ + t];
    }
    __syncthreads();

    const int ja = lane;
    const int jb = lane + 64;
    const bool ja_ok = (ja >= 1);
    const bool jb_ok = (jb <= NHUN);

    int   p_a = 0, p_b = 0;
    float v_a = 0.f, v_b = 0.f;
    float u_reg = 0.f;

    for (int i = 1; i <= T_; ++i) {
        float ca = ja_ok ? csh[(ja - 1) * CPAD + (i - 1)] : INFINITY;
        float cb = jb_ok ? csh[(jb - 1) * CPAD + (i - 1)] : INFINITY;
        float vmin = fminf(ca, cb);
        for (int off = 32; off > 0; off >>= 1)
            vmin = fminf(vmin, __shfl_xor(vmin, off));
        unsigned long long ba = __ballot(ca == vmin);
        int j1 = ba ? (__ffsll(ba) - 1) : (__ffsll(__ballot(cb == vmin)) - 1 + 64);
        if (lane == i) u_reg = vmin;
        int pj = __shfl((j1 < 64) ? p_a : p_b, j1 & 63);
        if (pj == 0) {
            if (j1 < 64) { if (lane == j1) p_a = i; }
            else         { if (lane == j1 - 64) p_b = i; }
        }
    }

    for (int i = 1; i <= T_; ++i) {
        bool mine = (p_a == i) || (p_b == i);
        if (__ballot(mine)) continue;

        float m_a = INFINITY, m_b = INFINITY;
        int   way_a = 0, way_b = 0;
        bool  us_a = false, us_b = false;
        bool  in_tree = (lane == i);
        int   j0 = 0, jf;

        while (true) {
            int i0 = (j0 == 0) ? i : __shfl((j0 < 64) ? p_a : p_b, j0 & 63);
            if (lane == i0) in_tree = true;
            float ui0 = __shfl(u_reg, i0);
            if (ja == j0) us_a = true;
            if (jb == j0) us_b = true;
            bool fa = ja_ok && !us_a;
            bool fb = jb_ok && !us_b;
            if (fa) {
                float cur = csh[(ja - 1) * CPAD + (i0 - 1)] - ui0 - v_a;
                if (cur < m_a) { m_a = cur; way_a = j0; }
            }
            if (fb) {
                float cur = csh[(jb - 1) * CPAD + (i0 - 1)] - ui0 - v_b;
                if (cur < m_b) { m_b = cur; way_b = j0; }
            }
            float ca = fa ? m_a : INFINITY;
            float cb = fb ? m_b : INFINITY;
            float vmin = fminf(ca, cb);
            for (int off = 32; off > 0; off >>= 1)
                vmin = fminf(vmin, __shfl_xor(vmin, off));
            unsigned long long ba = __ballot(ca == vmin);
            int j1 = ba ? (__ffsll(ba) - 1) : (__ffsll(__ballot(cb == vmin)) - 1 + 64);
            float delta = vmin;
            if (us_a) v_a -= delta; else m_a -= delta;
            if (us_b) v_b -= delta; else m_b -= delta;
            if (in_tree) u_reg += delta;
            j0 = j1;
            int pj0 = __shfl((j0 < 64) ? p_a : p_b, j0 & 63);
            if (pj0 == 0) { jf = j0; break; }
        }
        int jj = jf;
        while (jj) {
            int wv = __shfl((jj < 64) ? way_a : way_b, jj & 63);
            int pn = (wv == 0) ? i : __shfl((wv < 64) ? p_a : p_b, wv & 63);
            if (jj < 64) { if (lane == jj) p_a = pn; }
            else         { if (lane == jj - 64) p_b = pn; }
            jj = wv;
        }
    }

    if (ja_ok) psh[ja] = p_a;
    if (jb_ok) psh[jb] = p_b;
    if (lane == 0) psh[0] = 0;
    __syncthreads();
    if (lane == 0) {
        int* ob = out + b * 2 * T_;
        int k = 0;
        for (int j = 1; j <= NHUN; ++j) {
            if (psh[j] != 0) { ob[k] = j - 1; ob[T_ + k] = psh[j] - 1; ++k; }
        }
    }
}

extern "C" void kernel_launch(void* const* d_in, const int* in_sizes, int n_in,
                              void* d_out, int out_size, void* d_ws, size_t ws_size,
                              hipStream_t stream) {
    const float* mq     = (const float*)d_in[0];   // [2,100,256,256]
    const float* cl     = (const float*)d_in[1];   // [2,100,134]
    const float* ml     = (const float*)d_in[2];   // [2,20,512,512]
    const int*   labels = (const int*)d_in[3];     // [2,20]
    int* out = (int*)d_out;                        // [2,2,20] int32
    float* ws = (float*)d_ws;

    float* lab_ps = ws + LABPS_OFF;
    float* cc     = ws + CC_OFF;
    float* cost   = ws + COST_OFF;

    size_t need = (size_t)WS_END_F * 4;

    if (ws_size >= need) {
        unsigned short* labT = (unsigned short*)(ws + LABT_HI_F);
        float* part = ws + PART_OFF;
        float* Csum = ws + CSUM_OFF;
        hipLaunchKernelGGL(lab_prep_kernel,   dim3(B_, T_, 8), dim3(256), 0, stream,
                           ml, labT, lab_ps, 1);
        hipLaunchKernelGGL(focal_mfma_kernel, dim3(B_ * KSB * MT_), dim3(256), 0, stream,
                           mq, labT, part);
        hipLaunchKernelGGL(reduce_part_kernel, dim3(B_ * MT_, 33), dim3(256), 0, stream,
                           part, Csum);
        hipLaunchKernelGGL(compose_kernel,    dim3(B_ * MT_),  dim3(320), 0, stream,
                           Csum, cl, labels, lab_ps, cost);
    } else {
        hipLaunchKernelGGL(lab_prep_kernel,   dim3(B_, T_, 8), dim3(256), 0, stream,
                           ml, (unsigned short*)ws, lab_ps, 0);
        hipLaunchKernelGGL(class_cost_kernel, dim3(B_ * Q_),   dim3(64),  0, stream, cl, labels, cc);
        hipLaunchKernelGGL(mask_cost_mono_kernel, dim3(B_ * Q_), dim3(1024), 0, stream,
                           mq, ml, cc, lab_ps, cost);
    }
    hipLaunchKernelGGL(hungarian_kernel, dim3(B_), dim3(64), 0, stream, cost, out);
}

// Round 19
// 69.504 us; speedup vs baseline: 6.8555x; 1.0057x over previous
//
#include <hip/hip_runtime.h>
#include <hip/hip_bf16.h>
#include <math.h>

#define HW_   65536
#define B_    2
#define Q_    100
#define C_    134
#define T_    20
#define NHUN  100
#define MT_   7            // M-tiles of 16 queries (112 >= 100)
#define KSB   128          // K-split blocks per (b,mt)
#define BKCH  512          // k per block
#define PREC  1088         // part record stride (1024 frag + 16 F + 16 P + pad)
#define CPAD  21           // padded cost row stride (floats) in hungarian LDS

typedef __attribute__((ext_vector_type(8))) short bf16x8;
typedef __attribute__((ext_vector_type(4))) float f32x4;

// ws layout (float units)
#define LABPS_OFF  0                    // [2][20][8]
#define CC_OFF     512                  // [200][20] (fallback path only)
#define COST_OFF   4608                 // [200][20]
#define BASE_END   8704
#define LABT_HI_F  BASE_END                         // 2*20*65536 ushort = 1,310,720 floats
#define PART_OFF   (LABT_HI_F + 1310720)            // 1792 records * 1088 floats
#define CSUM_OFF   (PART_OFF + B_ * KSB * MT_ * PREC)   // 14*1056
#define WS_END_F   (CSUM_OFF + B_ * MT_ * 1056)

__device__ inline unsigned short f2bf(float f) {
    unsigned int u = __builtin_bit_cast(unsigned int, f);
    u += 0x7FFFu + ((u >> 16) & 1u);               // RNE
    return (unsigned short)(u >> 16);
}
__device__ inline float softplusf(float x) {
    float ax = fabsf(x);
    return fmaxf(x, 0.0f) + log1pf(expf(-ax));
}

// ---------------- K1: decimate labels -> bf16 rows [b][t][65536] + row-sum partials ----------------
__global__ void lab_prep_kernel(const float* __restrict__ ml, unsigned short* __restrict__ labT,
                                float* __restrict__ lab_ps, int writeT) {
    int b = blockIdx.x, t = blockIdx.y, ksl = blockIdx.z;
    int tid = threadIdx.x;
    const float* src = ml + (size_t)(b * T_ + t) * 262144;
    size_t dst = ((size_t)(b * T_ + t)) << 16;
    float acc = 0.f;
    for (int it = 0; it < 8; ++it) {
        int k = ksl * 8192 + it * 1024 + tid * 4;
        int r = k >> 8, c = k & 255;
        const float* s = src + r * 1024 + 2 * c;
        float4 u = *(const float4*)s;
        float4 w = *(const float4*)(s + 4);
        float v[4] = {u.x, u.z, w.x, w.z};
        unsigned short h[4];
#pragma unroll
        for (int e = 0; e < 4; ++e) { h[e] = f2bf(v[e]); acc += v[e]; }
        if (writeT) *(ushort4*)(labT + dst + k) = make_ushort4(h[0], h[1], h[2], h[3]);
    }
    for (int off = 32; off > 0; off >>= 1) acc += __shfl_down(acc, off);
    __shared__ float sb[4];
    int wid = tid >> 6, lane = tid & 63;
    if (lane == 0) sb[wid] = acc;
    __syncthreads();
    if (tid == 0) lab_ps[(b * T_ + t) * 8 + ksl] = sb[0] + sb[1] + sb[2] + sb[3];
}

// ---------------- class cost (fallback path only) ----------------
__global__ void class_cost_kernel(const float* __restrict__ cl, const int* __restrict__ labels,
                                  float* __restrict__ cc) {
    int bq  = blockIdx.x;
    int b   = bq / Q_;
    int tid = threadIdx.x;         // 64
    __shared__ float sl[C_];
    const float* src = cl + (size_t)bq * C_;
    for (int c = tid; c < C_; c += 64) sl[c] = src[c];
    __syncthreads();
    float mx = -INFINITY;
    for (int c = tid; c < C_; c += 64) mx = fmaxf(mx, sl[c]);
    for (int off = 32; off > 0; off >>= 1) mx = fmaxf(mx, __shfl_xor(mx, off));
    float se = 0.f;
    for (int c = tid; c < C_; c += 64) se += expf(sl[c] - mx);
    for (int off = 32; off > 0; off >>= 1) se += __shfl_xor(se, off);
    float inv = 1.0f / se;
    if (tid < T_) {
        int lbl = labels[b * T_ + tid];
        cc[bq * T_ + tid] = -expf(sl[lbl] - mx) * inv;
    }
}

// ---------------- K3: focal MFMA with full-block prefetch + XCD-aware block swizzle ----------------
// Logical idx = (b*KSB + ks)*MT_ + mt. HW round-robins blockIdx across 8 XCDs; the
// bijective swizzle idx=(bid&7)*224+(bid>>3) (1792%8==0) puts consecutive LOGICAL
// blocks (same ks -> shared labT chunk) on the SAME XCD for L2 reuse. [T1, m192]
__global__ __launch_bounds__(256, 4) void focal_mfma_kernel(
        const float* __restrict__ mq, const unsigned short* __restrict__ labT,
        float* __restrict__ part) {
    int bid = blockIdx.x;                      // 0..1791
    int idx = (bid & 7) * 224 + (bid >> 3);    // XCD-aware remap (bijection)
    int mt  = idx % MT_;
    int rem = idx / MT_;
    int ks  = rem % KSB;
    int b   = rem / KSB;
    int tid  = threadIdx.x;
    int wave = tid >> 6, lane = tid & 63;
    int lg = lane >> 4, lr = lane & 15;

    int q = mt * 16 + lr;
    bool qok = (q < Q_);
    const float* xrow = mq + ((size_t)(b * Q_ + (qok ? q : 0)) << 16);
    int koff = ks * BKCH + wave * 128 + lg * 8;

    const unsigned short* b1 = labT + (((size_t)(b * T_ + lr)) << 16);
    const unsigned short* b2 = labT + (((size_t)(b * T_ + 16 + (lr & 3))) << 16);
    bool n2row = (lr < 4);

    bf16x8 zer;
#pragma unroll
    for (int e = 0; e < 8; ++e) zer[e] = 0;

    // ---- prefetch: 16 independent loads in flight ----
    float4 a0[4], a1[4];
    bf16x8 bfrag1[4], bfrag2[4];
#pragma unroll
    for (int kk = 0; kk < 4; ++kk) {
        int kb = koff + kk * 32;
        a0[kk] = *(const float4*)(xrow + kb);
        a1[kk] = *(const float4*)(xrow + kb + 4);
        bfrag1[kk] = *(const bf16x8*)(b1 + kb);
        bfrag2[kk] = n2row ? *(const bf16x8*)(b2 + kb) : zer;
    }

    f32x4 accD0 = {0,0,0,0}, accD1 = {0,0,0,0};
    f32x4 accP0 = {0,0,0,0}, accP1 = {0,0,0,0};
    float F = 0.f, P = 0.f;

#pragma unroll
    for (int kk = 0; kk < 4; ++kk) {
        float xv[8] = {a0[kk].x, a0[kk].y, a0[kk].z, a0[kk].w,
                       a1[kk].x, a1[kk].y, a1[kk].z, a1[kk].w};
        bf16x8 dh, ph;
#pragma unroll
        for (int e = 0; e < 8; ++e) {
            float x  = xv[e];
            float ax = fabsf(x);
            float a  = __expf(-ax);
            float rr = 1.0f / (1.0f + a);
            float p  = (x >= 0.f) ? rr : a * rr;
            float om = (x >= 0.f) ? a * rr : rr;
            float l1 = __logf(1.0f + a);
            float spn = fmaxf(-x, 0.f) + l1;
            float spp = spn + x;
            float fp = 0.25f * om * om * spn;
            float fn = 0.75f * p * p * spp;
            F += fn; P += p;
            dh[e] = (short)f2bf(fp - fn);
            ph[e] = (short)f2bf(p);
        }
        accD0 = __builtin_amdgcn_mfma_f32_16x16x32_bf16(dh, bfrag1[kk], accD0, 0, 0, 0);
        accD1 = __builtin_amdgcn_mfma_f32_16x16x32_bf16(dh, bfrag2[kk], accD1, 0, 0, 0);
        accP0 = __builtin_amdgcn_mfma_f32_16x16x32_bf16(ph, bfrag1[kk], accP0, 0, 0, 0);
        accP1 = __builtin_amdgcn_mfma_f32_16x16x32_bf16(ph, bfrag2[kk], accP1, 0, 0, 0);
    }

    F += __shfl_down(F, 32); F += __shfl_down(F, 16);
    P += __shfl_down(P, 32); P += __shfl_down(P, 16);

    __shared__ float red[4][4][64][4];
    __shared__ float fpb[4][2][16];
#pragma unroll
    for (int r = 0; r < 4; ++r) {
        red[wave][0][lane][r] = accD0[r];
        red[wave][1][lane][r] = accD1[r];
        red[wave][2][lane][r] = accP0[r];
        red[wave][3][lane][r] = accP1[r];
    }
    if (lane < 16) { fpb[wave][0][lane] = F; fpb[wave][1][lane] = P; }
    __syncthreads();
    {
        int e4 = tid;                      // 256 float4 groups = 1024 floats
        int f  = e4 >> 6;                  // frag id 0..3
        int l2 = e4 & 63;                  // lane idx
        float4 s;
        s.x = red[0][f][l2][0] + red[1][f][l2][0] + red[2][f][l2][0] + red[3][f][l2][0];
        s.y = red[0][f][l2][1] + red[1][f][l2][1] + red[2][f][l2][1] + red[3][f][l2][1];
        s.z = red[0][f][l2][2] + red[1][f][l2][2] + red[2][f][l2][2] + red[3][f][l2][2];
        s.w = red[0][f][l2][3] + red[1][f][l2][3] + red[2][f][l2][3] + red[3][f][l2][3];
        *(float4*)(part + (size_t)idx * PREC + e4 * 4) = s;
    }
    if (tid < 16)
        part[(size_t)idx * PREC + 1024 + tid] =
            fpb[0][0][tid] + fpb[1][0][tid] + fpb[2][0][tid] + fpb[3][0][tid];
    else if (tid < 32) {
        int l = tid - 16;
        part[(size_t)idx * PREC + 1040 + l] =
            fpb[0][1][l] + fpb[1][1][l] + fpb[2][1][l] + fpb[3][1][l];
    }
}

// ---------------- K4a: parallel K-split reduction: part -> Csum[14][1056] ----------------
__global__ __launch_bounds__(256) void reduce_part_kernel(const float* __restrict__ part,
                                                          float* __restrict__ Csum) {
    int bm   = blockIdx.x;          // 0..13
    int mt   = bm % MT_;
    int b    = bm / MT_;
    int tid  = threadIdx.x;
    int epos = tid & 31;
    int grp  = tid >> 5;            // 0..7
    int e    = blockIdx.y * 32 + epos;   // 0..1055

    const float* base = part + (size_t)((b * KSB) * MT_ + mt) * PREC + e;
    float s = 0.f;
    for (int k = 0; k < 16; ++k) {
        s += base[(size_t)(grp * 16 + k) * MT_ * PREC];
    }
    __shared__ float red[8][33];
    red[grp][epos] = s;
    __syncthreads();
    if (tid < 32) {
        float tot = 0.f;
        for (int g = 0; g < 8; ++g) tot += red[g][tid];
        Csum[(size_t)bm * 1056 + e] = tot;
    }
}

// ---------------- K4b: finalize cost from Csum + fused class-softmax (R8-proven) ----------------
__global__ __launch_bounds__(320) void compose_kernel(
        const float* __restrict__ Csum, const float* __restrict__ cl,
        const int* __restrict__ labels, const float* __restrict__ lab_ps,
        float* __restrict__ cost) {
    int bm = blockIdx.x;
    int mt = bm % MT_;
    int b  = bm / MT_;
    int tid = threadIdx.x;     // 320
    int q0 = mt * 16;

    __shared__ float sl[16][136];
    __shared__ float mx[16], se[16];
    __shared__ int   lbl[T_];
    for (int e = tid; e < 16 * C_; e += 320) {
        int qm = e / C_, c = e % C_;
        int q = q0 + qm;
        sl[qm][c] = (q < Q_) ? cl[(size_t)(b * Q_ + q) * C_ + c] : 0.f;
    }
    if (tid < T_) lbl[tid] = labels[b * T_ + tid];
    __syncthreads();
    if (tid < 16) {
        float m = -INFINITY;
        for (int c = 0; c < C_; ++c) m = fmaxf(m, sl[tid][c]);
        float s = 0.f;
        for (int c = 0; c < C_; ++c) s += expf(sl[tid][c] - m);
        mx[tid] = m; se[tid] = s;
    }
    __syncthreads();

    int qm = tid / T_, t = tid % T_;
    int q = q0 + qm;
    if (qm < 16 && q < Q_) {
        const float* C = Csum + (size_t)bm * 1056;
        int nt   = t >> 4;
        int lane = ((qm >> 2) << 4) | (t & 15);
        int reg  = qm & 3;
        float Sd = C[(0 + nt) * 256 + lane * 4 + reg];
        float Sp = C[(2 + nt) * 256 + lane * 4 + reg];
        float F  = C[1024 + qm];
        float P  = C[1040 + qm];
        float L = 0.f;
        for (int s8 = 0; s8 < 8; ++s8) L += lab_ps[(b * T_ + t) * 8 + s8];
        float ccv = -expf(sl[qm][lbl[t]] - mx[qm]) / se[qm];
        float cm = (Sd + F) * (1.0f / (float)HW_);
        float cd = 1.0f - (2.0f * Sp + 1.0f) / (P + L + 1.0f);
        cost[(size_t)(b * Q_ + q) * T_ + t] = cm + cd + ccv;
    }
}

// ---------------- fallback: monolithic (round-2 proven) ----------------
__global__ __launch_bounds__(1024) void mask_cost_mono_kernel(
        const float* __restrict__ mq, const float* __restrict__ ml,
        const float* __restrict__ cc, const float* __restrict__ lab_ps,
        float* __restrict__ cost) {
    int bq  = blockIdx.x;
    int b   = bq / Q_;
    int tid = threadIdx.x;
    const float* xb  = mq + (size_t)bq * HW_;
    const float* mlb = ml + (size_t)b * T_ * 262144;
    float s1[T_], s2[T_];
#pragma unroll
    for (int t = 0; t < T_; ++t) { s1[t] = 0.f; s2[t] = 0.f; }
    float F = 0.f, P = 0.f;
    for (int k = tid; k < HW_; k += 1024) {
        int i = k >> 8, j = k & 255;
        float x = xb[k];
        float p = 1.0f / (1.0f + expf(-x));
        float spn = softplusf(-x);
        float spp = softplusf(x);
        float om = 1.0f - p;
        float fp = 0.25f * om * om * spn;
        float fn = 0.75f * p * p * spp;
        F += fn; P += p;
        float diff = fp - fn;
        int off0 = i * 1024 + 2 * j;
#pragma unroll
        for (int t = 0; t < T_; ++t) {
            float lab = mlb[t * 262144 + off0];
            s1[t] = fmaf(diff, lab, s1[t]);
            s2[t] = fmaf(p,    lab, s2[t]);
        }
    }
    __shared__ float sbuf[16][42];
    int wid = tid >> 6, lane = tid & 63;
#pragma unroll
    for (int t = 0; t < T_; ++t) {
        for (int off = 32; off > 0; off >>= 1) {
            s1[t] += __shfl_down(s1[t], off);
            s2[t] += __shfl_down(s2[t], off);
        }
    }
    for (int off = 32; off > 0; off >>= 1) { F += __shfl_down(F, off); P += __shfl_down(P, off); }
    if (lane == 0) {
#pragma unroll
        for (int t = 0; t < T_; ++t) { sbuf[wid][t] = s1[t]; sbuf[wid][T_ + t] = s2[t]; }
        sbuf[wid][40] = F; sbuf[wid][41] = P;
    }
    __syncthreads();
    if (tid < T_) {
        float S1 = 0.f, S2 = 0.f, Fs = 0.f, Ps = 0.f;
        for (int w = 0; w < 16; ++w) {
            S1 += sbuf[w][tid]; S2 += sbuf[w][T_ + tid];
            Fs += sbuf[w][40];  Ps += sbuf[w][41];
        }
        float L = 0.f;
        for (int sl = 0; sl < 8; ++sl) L += lab_ps[(b * T_ + tid) * 8 + sl];
        float cm = (S1 + Fs) * (1.0f / (float)HW_);
        float cd = 1.0f - (2.0f * S2 + 1.0f) / (Ps + L + 1.0f);
        cost[bq * T_ + tid] = cm + cd + cc[bq * T_ + tid];
    }
}

// ---------------- K5: register-resident JV Hungarian with greedy row-reduction init (R12-proven) ----------------
__global__ __launch_bounds__(64) void hungarian_kernel(const float* __restrict__ cost,
                                                       int* __restrict__ out) {
    int b    = blockIdx.x;
    int lane = threadIdx.x;

    __shared__ float csh[Q_ * CPAD];
    __shared__ int   psh[NHUN + 1];

    for (int j = lane; j < Q_; j += 64) {
#pragma unroll
        for (int t = 0; t < T_; ++t)
            csh[j * CPAD + t] = cost[b * Q_ * T_ + j * T_ + t];
    }
    __syncthreads();

    const int ja = lane;
    const int jb = lane + 64;
    const bool ja_ok = (ja >= 1);
    const bool jb_ok = (jb <= NHUN);

    int   p_a = 0, p_b = 0;
    float v_a = 0.f, v_b = 0.f;
    float u_reg = 0.f;

    for (int i = 1; i <= T_; ++i) {
        float ca = ja_ok ? csh[(ja - 1) * CPAD + (i - 1)] : INFINITY;
        float cb = jb_ok ? csh[(jb - 1) * CPAD + (i - 1)] : INFINITY;
        float vmin = fminf(ca, cb);
        for (int off = 32; off > 0; off >>= 1)
            vmin = fminf(vmin, __shfl_xor(vmin, off));
        unsigned long long ba = __ballot(ca == vmin);
        int j1 = ba ? (__ffsll(ba) - 1) : (__ffsll(__ballot(cb == vmin)) - 1 + 64);
        if (lane == i) u_reg = vmin;
        int pj = __shfl((j1 < 64) ? p_a : p_b, j1 & 63);
        if (pj == 0) {
            if (j1 < 64) { if (lane == j1) p_a = i; }
            else         { if (lane == j1 - 64) p_b = i; }
        }
    }

    for (int i = 1; i <= T_; ++i) {
        bool mine = (p_a == i) || (p_b == i);
        if (__ballot(mine)) continue;

        float m_a = INFINITY, m_b = INFINITY;
        int   way_a = 0, way_b = 0;
        bool  us_a = false, us_b = false;
        bool  in_tree = (lane == i);
        int   j0 = 0, jf;

        while (true) {
            int i0 = (j0 == 0) ? i : __shfl((j0 < 64) ? p_a : p_b, j0 & 63);
            if (lane == i0) in_tree = true;
            float ui0 = __shfl(u_reg, i0);
            if (ja == j0) us_a = true;
            if (jb == j0) us_b = true;
            bool fa = ja_ok && !us_a;
            bool fb = jb_ok && !us_b;
            if (fa) {
                float cur = csh[(ja - 1) * CPAD + (i0 - 1)] - ui0 - v_a;
                if (cur < m_a) { m_a = cur; way_a = j0; }
            }
            if (fb) {
                float cur = csh[(jb - 1) * CPAD + (i0 - 1)] - ui0 - v_b;
                if (cur < m_b) { m_b = cur; way_b = j0; }
            }
            float ca = fa ? m_a : INFINITY;
            float cb = fb ? m_b : INFINITY;
            float vmin = fminf(ca, cb);
            for (int off = 32; off > 0; off >>= 1)
                vmin = fminf(vmin, __shfl_xor(vmin, off));
            unsigned long long ba = __ballot(ca == vmin);
            int j1 = ba ? (__ffsll(ba) - 1) : (__ffsll(__ballot(cb == vmin)) - 1 + 64);
            float delta = vmin;
            if (us_a) v_a -= delta; else m_a -= delta;
            if (us_b) v_b -= delta; else m_b -= delta;
            if (in_tree) u_reg += delta;
            j0 = j1;
            int pj0 = __shfl((j0 < 64) ? p_a : p_b, j0 & 63);
            if (pj0 == 0) { jf = j0; break; }
        }
        int jj = jf;
        while (jj) {
            int wv = __shfl((jj < 64) ? way_a : way_b, jj & 63);
            int pn = (wv == 0) ? i : __shfl((wv < 64) ? p_a : p_b, wv & 63);
            if (jj < 64) { if (lane == jj) p_a = pn; }
            else         { if (lane == jj - 64) p_b = pn; }
            jj = wv;
        }
    }

    if (ja_ok) psh[ja] = p_a;
    if (jb_ok) psh[jb] = p_b;
    if (lane == 0) psh[0] = 0;
    __syncthreads();
    if (lane == 0) {
        int* ob = out + b * 2 * T_;
        int k = 0;
        for (int j = 1; j <= NHUN; ++j) {
            if (psh[j] != 0) { ob[k] = j - 1; ob[T_ + k] = psh[j] - 1; ++k; }
        }
    }
}

extern "C" void kernel_launch(void* const* d_in, const int* in_sizes, int n_in,
                              void* d_out, int out_size, void* d_ws, size_t ws_size,
                              hipStream_t stream) {
    const float* mq     = (const float*)d_in[0];   // [2,100,256,256]
    const float* cl     = (const float*)d_in[1];   // [2,100,134]
    const float* ml     = (const float*)d_in[2];   // [2,20,512,512]
    const int*   labels = (const int*)d_in[3];     // [2,20]
    int* out = (int*)d_out;                        // [2,2,20] int32
    float* ws = (float*)d_ws;

    float* lab_ps = ws + LABPS_OFF;
    float* cc     = ws + CC_OFF;
    float* cost   = ws + COST_OFF;

    size_t need = (size_t)WS_END_F * 4;

    if (ws_size >= need) {
        unsigned short* labT = (unsigned short*)(ws + LABT_HI_F);
        float* part = ws + PART_OFF;
        float* Csum = ws + CSUM_OFF;
        hipLaunchKernelGGL(lab_prep_kernel,   dim3(B_, T_, 8), dim3(256), 0, stream,
                           ml, labT, lab_ps, 1);
        hipLaunchKernelGGL(focal_mfma_kernel, dim3(B_ * KSB * MT_), dim3(256), 0, stream,
                           mq, labT, part);
        hipLaunchKernelGGL(reduce_part_kernel, dim3(B_ * MT_, 33), dim3(256), 0, stream,
                           part, Csum);
        hipLaunchKernelGGL(compose_kernel,    dim3(B_ * MT_),  dim3(320), 0, stream,
                           Csum, cl, labels, lab_ps, cost);
    } else {
        hipLaunchKernelGGL(lab_prep_kernel,   dim3(B_, T_, 8), dim3(256), 0, stream,
                           ml, (unsigned short*)ws, lab_ps, 0);
        hipLaunchKernelGGL(class_cost_kernel, dim3(B_ * Q_),   dim3(64),  0, stream, cl, labels, cc);
        hipLaunchKernelGGL(mask_cost_mono_kernel, dim3(B_ * Q_), dim3(1024), 0, stream,
                           mq, ml, cc, lab_ps, cost);
    }
    hipLaunchKernelGGL(hungarian_kernel, dim3(B_), dim3(64), 0, stream, cost, out);
}